// Round 3
// baseline (388.934 us; speedup 1.0000x reference)
//
#include <hip/hip_runtime.h>

#define Nq 300
#define Tq 12
#define Dq 64
#define Mq 16
#define BTq 384
#define DDq (Dq*Dq)      // 4096
#define Fq (Dq*3)        // 192
#define NP 320           // padded k-extent of transposed bf16 buffers

typedef short bf8_t __attribute__((ext_vector_type(8)));
typedef float f4_t  __attribute__((ext_vector_type(4)));

__device__ __forceinline__ unsigned short f2bf(float f) {
    unsigned u = __float_as_uint(f);
    u = (u + 0x7FFFu + ((u >> 16) & 1u)) >> 16;
    return (unsigned short)u;
}
__device__ __forceinline__ float bf2f(unsigned short u) {
    return __uint_as_float((unsigned)u << 16);
}
__device__ __forceinline__ float4 ld4(const float* p) { return *(const float4*)p; }

__device__ __forceinline__ bf8_t pack8(float4 a, float4 b) {
    bf8_t r;
    r[0] = (short)f2bf(a.x); r[1] = (short)f2bf(a.y);
    r[2] = (short)f2bf(a.z); r[3] = (short)f2bf(a.w);
    r[4] = (short)f2bf(b.x); r[5] = (short)f2bf(b.y);
    r[6] = (short)f2bf(b.z); r[7] = (short)f2bf(b.w);
    return r;
}

__device__ __forceinline__ float gatef(float p) {
    float pc = fminf(fmaxf(p, -30.f), 30.f);
    float sig = 1.f / (1.f + __expf(-pc));
    float e2  = __expf(2.f * pc);
    float th  = (e2 - 1.f) / (e2 + 1.f);
    return sig * th;
}

// ---- Merged front-end: 1548 blocks.
__global__ void __launch_bounds__(256) kprep_all(
    const float* __restrict__ a1, const float* __restrict__ a2,
    const float* __restrict__ b1, const float* __restrict__ b2,
    const float* __restrict__ w1, const float* __restrict__ w2,
    const float* __restrict__ adjW, const float* __restrict__ adjB,
    const float* __restrict__ X,
    unsigned* __restrict__ ABt, unsigned short* __restrict__ Wt,
    unsigned short* __restrict__ adjWb, float* __restrict__ adjBp,
    unsigned short* __restrict__ Xp_t, unsigned short* __restrict__ Xp_nb)
{
    __shared__ char smem[64 * 308 * 2];    // 39424 B union (only [32][308]*2B used by X path)
    const int vb = blockIdx.x;
    const int tid = threadIdx.x;

    if (vb < 400) {
        const int tile = vb;
        const int reg = tid & 3, lane = tid >> 2;
        const int nt = tile % 5;  int r1 = tile / 5;
        const int w  = r1 % 4;    int r2 = r1 / 4;
        const int c  = r2 % 5;    const int qi = r2 / 5;
        const int n = qi*80 + nt*16 + (lane & 15);
        const int k = c*64 + w*16 + (lane >> 4)*4 + reg;
        unsigned outv = 0u;
        if (n < Nq && k < Nq) {
            float sa = 0.f, sb = 0.f;
            #pragma unroll
            for (int m = 0; m < Mq; ++m) {
                sa = fmaf(a1[n*Mq+m], a2[m*Nq+k], sa);
                sb = fmaf(b1[n*Mq+m], b2[m*Nq+k], sb);
            }
            outv = ((unsigned)f2bf(sb) << 16) | (unsigned)f2bf(sa);
        }
        ABt[tile*256 + tid] = outv;
    } else if (vb < 700) {
        float* sT = (float*)smem;          // [64][65]
        __shared__ float sw1[Mq];
        const int n = vb - 400;
        if (tid < Mq) sw1[tid] = w1[n*Mq + tid];
        __syncthreads();
        for (int i = tid; i < DDq; i += 256) {
            int k = i >> 6, d = i & 63;
            float s = 0.f;
            #pragma unroll
            for (int m = 0; m < Mq; ++m) s = fmaf(sw1[m], w2[m*DDq + i], s);
            sT[d*65 + k] = s;
        }
        __syncthreads();
        for (int i = tid; i < DDq; i += 256) {
            int d = i >> 6, k = i & 63;
            Wt[(size_t)n*DDq + i] = f2bf(sT[d*65 + k]);
        }
    } else if (vb < 780) {
        int e = (vb - 700) * 256 + tid;
        if (e < NP * 64) {
            int k = e >> 6, d = e & 63;
            adjWb[e] = (k < Nq) ? f2bf(adjW[k*Dq + d]) : (unsigned short)0;
        }
        if (e < NP) adjBp[e] = (e < Nq) ? adjB[e] : 0.f;
    } else {
        // X [b][d][n][t] -> Xp_t bf16 [bt][64][320] and Xp_nb bf16 [n][384][64]
        unsigned short* sT = (unsigned short*)smem;   // [32][308]
        const int bx = vb - 780;
        const int b = bx / 24, sub = bx % 24;
        const int tile = sub >> 1, half = sub & 1;
        const int n0 = tile * 25, d0 = half * 32;
        for (int i = tid; i < 32 * 75; i += 256) {
            int dl = i / 75, jq = i - dl*75, j = jq*4;
            float4 v = ld4(&X[(size_t)(b*64 + d0 + dl)*3600 + n0*12 + j]);
            ushort4 o;
            o.x = f2bf(v.x); o.y = f2bf(v.y); o.z = f2bf(v.z); o.w = f2bf(v.w);
            *(ushort4*)&sT[dl*308 + j] = o;
        }
        __syncthreads();
        for (int wi = tid; wi < 12 * 32 * 25; wi += 256) {
            int nl = wi % 25, rem = wi / 25;
            int dl = rem & 31, t = rem >> 5;
            Xp_t[((size_t)(b*Tq + t)*64 + d0 + dl)*NP + n0 + nl] = sT[dl*308 + nl*12 + t];
        }
        if (tile == 11) {
            for (int wi = tid; wi < 12 * 32 * 20; wi += 256) {
                int e = wi % 20, rem = wi / 20;
                int dl = rem & 31, t = rem >> 5;
                Xp_t[((size_t)(b*Tq + t)*64 + d0 + dl)*NP + 300 + e] = 0;
            }
        }
        for (int wi = tid; wi < 25 * 12 * 8; wi += 256) {
            int dg = wi & 7, rem = wi >> 3;
            int t = rem % 12, nl = rem / 12;
            ushort4 o;
            o.x = sT[(dg*4+0)*308 + nl*12 + t];
            o.y = sT[(dg*4+1)*308 + nl*12 + t];
            o.z = sT[(dg*4+2)*308 + nl*12 + t];
            o.w = sT[(dg*4+3)*308 + nl*12 + t];
            *(ushort4*)&Xp_nb[((size_t)(n0+nl)*BTq + b*Tq + t)*64 + d0 + dg*4] = o;
        }
    }
}

// bf16 transpose: H_nb [n][384][64] -> H_t [bt][64][320] (cols>=300 zero)
__global__ void __launch_bounds__(256) ktr2(const unsigned short* __restrict__ Hnb,
                                            unsigned short* __restrict__ Ht) {
    __shared__ unsigned short sT[64 * 308];
    const int bt = blockIdx.x;
    const int tid = threadIdx.x;
    for (int i = tid; i < 300 * 16; i += 256) {
        int nl = i >> 4, dg = i & 15;
        ushort4 v = *(const ushort4*)&Hnb[((size_t)nl*BTq + bt)*64 + dg*4];
        sT[(dg*4+0)*308 + nl] = v.x;
        sT[(dg*4+1)*308 + nl] = v.y;
        sT[(dg*4+2)*308 + nl] = v.z;
        sT[(dg*4+3)*308 + nl] = v.w;
    }
    __syncthreads();
    for (int wi = tid; wi < 64 * 80; wi += 256) {
        int kq = wi % 80, d = wi / 80;
        ushort4 o;
        int k = kq * 4;
        o.x = (k+0 < Nq) ? sT[d*308 + k+0] : (unsigned short)0;
        o.y = (k+1 < Nq) ? sT[d*308 + k+1] : (unsigned short)0;
        o.z = (k+2 < Nq) ? sT[d*308 + k+2] : (unsigned short)0;
        o.w = (k+3 < Nq) ? sT[d*308 + k+3] : (unsigned short)0;
        *(ushort4*)&Ht[((size_t)bt*64 + d)*NP + k] = o;
    }
}

// Fused A-recompute + aggregation, WAVE-INDEPENDENT version: no __syncthreads,
// wave-private LDS slice for the D-frag -> B-frag repack. Each wave owns 16 n-rows.
// Grid 1920 = 384 bt x 5 blocks; 4 waves/block -> 20 groups (19 used).
template<int HOP>
__global__ void __launch_bounds__(256) kfuse_t(
    const float* __restrict__ te,              // [B,N,T,D] fp32 (original input)
    unsigned short* __restrict__ teP,          // [bt][300][64] bf16 (HOP1 write / HOP2 read)
    const unsigned short* __restrict__ adjWb,  // [320][64]
    const float* __restrict__ adjBp,           // [320]
    const unsigned* __restrict__ ABt,          // tiled pairs
    const unsigned short* __restrict__ Hb_t,   // [bt][64][320]
    unsigned short* __restrict__ Hout_nb)      // [300][384][64]
{
    __shared__ unsigned short sP[4][16 * 72];  // per-wave slice: 16 n-rows x 72 (k 0..63 + pad)
    const int bt = blockIdx.x / 5, blkq = blockIdx.x % 5;
    const int b = bt / Tq, t = bt - b * Tq;
    const int tid = threadIdx.x;
    const int wid = tid >> 6, lane = tid & 63, quad = lane >> 4, l16 = lane & 15;
    const int group = blkq * 4 + wid;          // 0..19 (19 = padding wave)
    const int qi = group / 5, nt = group % 5;
    const int n0 = group * 16;
    const int n = n0 + l16;
    const int nc = (n > Nq-1) ? (Nq-1) : n;
    unsigned short* sp = sP[wid];

    // te fragments: B-op rows d=quad*8+j, col n=l16 (this wave's own rows)
    bf8_t tb0, tb1;
    if (HOP == 1) {
        const float* ter = te + (((size_t)b*Nq + nc)*Tq + t)*Dq;
        tb0 = pack8(ld4(ter + quad*8),      ld4(ter + quad*8 + 4));
        tb1 = pack8(ld4(ter + 32 + quad*8), ld4(ter + 36 + quad*8));
        if (n < Nq) {
            *(bf8_t*)&teP[((size_t)bt*Nq + n)*64 + quad*8] = tb0;
            *(bf8_t*)&teP[((size_t)bt*Nq + n)*64 + 32 + quad*8] = tb1;
        }
    } else {
        const unsigned short* tr = teP + ((size_t)bt*Nq + nc)*64;
        tb0 = *(const bf8_t*)(tr + quad*8);
        tb1 = *(const bf8_t*)(tr + 32 + quad*8);
    }

    f4_t accO[4];
    #pragma unroll
    for (int db = 0; db < 4; ++db) accO[db] = (f4_t){0.f, 0.f, 0.f, 0.f};

    const unsigned short* hrow = Hb_t + (size_t)bt*64*NP;

    for (int c = 0; c < 5; ++c) {
        const int cbase = c * 64;
        // alpha/beta pairs for (n=n0+l16, k=cbase+kb*16+quad*4+reg)
        const unsigned* abq = ABt + ((((size_t)qi*5 + c)*4)*5 + nt)*256 + (quad*16 + l16)*4;
        uint4 abv[4];
        #pragma unroll
        for (int kb = 0; kb < 4; ++kb) abv[kb] = *(const uint4*)(abq + kb*5*256);

        #pragma unroll
        for (int kb = 0; kb < 4; ++kb) {
            // adjW A-op: row k=cbase+kb*16+l16, contraction d=half*32+quad*8+j
            const unsigned short* ar = adjWb + (cbase + kb*16 + l16)*64;
            bf8_t ka0 = *(const bf8_t*)(ar + quad*8);
            bf8_t ka1 = *(const bf8_t*)(ar + 32 + quad*8);
            f4_t pd = {0.f, 0.f, 0.f, 0.f};
            pd = __builtin_amdgcn_mfma_f32_16x16x32_bf16(ka0, tb0, pd, 0, 0, 0);
            pd = __builtin_amdgcn_mfma_f32_16x16x32_bf16(ka1, tb1, pd, 0, 0, 0);
            // pd[reg]: P-pre at (k=cbase+kb*16+quad*4+reg, n=n0+l16)
            float4 bias4 = ld4(adjBp + cbase + kb*16 + quad*4);
            uint4 ab = abv[kb];
            unsigned r0, r1, r2, r3;
            {
                float sv = __sinf(pd[0] + bias4.x);
                r0 = f2bf(fmaxf(fmaf(__uint_as_float(ab.x << 16), sv,
                                     __uint_as_float(ab.x & 0xFFFF0000u)), 0.f));
            }
            {
                float sv = __sinf(pd[1] + bias4.y);
                r1 = f2bf(fmaxf(fmaf(__uint_as_float(ab.y << 16), sv,
                                     __uint_as_float(ab.y & 0xFFFF0000u)), 0.f));
            }
            {
                float sv = __sinf(pd[2] + bias4.z);
                r2 = f2bf(fmaxf(fmaf(__uint_as_float(ab.z << 16), sv,
                                     __uint_as_float(ab.z & 0xFFFF0000u)), 0.f));
            }
            {
                float sv = __sinf(pd[3] + bias4.w);
                r3 = f2bf(fmaxf(fmaf(__uint_as_float(ab.w << 16), sv,
                                     __uint_as_float(ab.w & 0xFFFF0000u)), 0.f));
            }
            // row n=l16, k-local = kb*16+quad*4 .. +3  (wave-private slice, same-wave order)
            *(uint2*)&sp[l16*72 + kb*16 + quad*4] =
                make_uint2((r1 << 16) | r0, (r3 << 16) | r2);
        }
        // B-frag read: B[k=h*32+quad*8+j][n=l16]
        bf8_t pb0 = *(const bf8_t*)&sp[l16*72 + quad*8];
        bf8_t pb1 = *(const bf8_t*)&sp[l16*72 + 32 + quad*8];
        #pragma unroll
        for (int db = 0; db < 4; ++db) {
            const unsigned short* hr = hrow + (size_t)(db*16 + l16)*NP + cbase;
            bf8_t hv0 = *(const bf8_t*)(hr + quad*8);
            bf8_t hv1 = *(const bf8_t*)(hr + 32 + quad*8);
            accO[db] = __builtin_amdgcn_mfma_f32_16x16x32_bf16(hv0, pb0, accO[db], 0, 0, 0);
            accO[db] = __builtin_amdgcn_mfma_f32_16x16x32_bf16(hv1, pb1, accO[db], 0, 0, 0);
        }
    }
    // accO[db][reg] = Hnow^T[d = db*16+quad*4+reg][n = n0+l16]
    if (n < Nq) {
        #pragma unroll
        for (int db = 0; db < 4; ++db) {
            ushort4 o;
            o.x = f2bf(accO[db][0]); o.y = f2bf(accO[db][1]);
            o.z = f2bf(accO[db][2]); o.w = f2bf(accO[db][3]);
            *(ushort4*)&Hout_nb[((size_t)n*BTq + bt)*64 + db*16 + quad*4] = o;
        }
    }
}

// Per-node matmul + gate. grid 1200 = (n, bt-quarter of 96).
__global__ void __launch_bounds__(256) kmm(
    const unsigned short* __restrict__ Hagg_nb,  // [n][384][64]
    const unsigned short* __restrict__ Xp_nb,    // [n][384][64]
    const unsigned short* __restrict__ Wt,       // [n][64][64]
    unsigned short* __restrict__ Hout_nb)        // [n][384][64]
{
    const int n = blockIdx.x >> 2, qi = blockIdx.x & 3;
    const int bt0 = qi * 96;
    const int tid = threadIdx.x;
    const int w = tid >> 6, lane = tid & 63, quad = lane >> 4, l16 = lane & 15;
    const int dcol = w*16 + l16;
    const unsigned short* wn = Wt + (size_t)n * DDq + dcol*64;
    bf8_t v0 = *(const bf8_t*)(wn + quad*8);
    bf8_t v1 = *(const bf8_t*)(wn + 32 + quad*8);
    bf8_t a0[6], a1[6];
    #pragma unroll
    for (int rt = 0; rt < 6; ++rt) {
        int r = bt0 + rt*16 + l16;
        const unsigned short* row = Hagg_nb + ((size_t)n*BTq + r)*64;
        a0[rt] = *(const bf8_t*)(row + quad*8);
        a1[rt] = *(const bf8_t*)(row + 32 + quad*8);
    }
    f4_t acc[6];
    #pragma unroll
    for (int rt = 0; rt < 6; ++rt) acc[rt] = (f4_t){0.f, 0.f, 0.f, 0.f};
    #pragma unroll
    for (int rt = 0; rt < 6; ++rt) {
        acc[rt] = __builtin_amdgcn_mfma_f32_16x16x32_bf16(v0, a0[rt], acc[rt], 0, 0, 0);
        acc[rt] = __builtin_amdgcn_mfma_f32_16x16x32_bf16(v1, a1[rt], acc[rt], 0, 0, 0);
    }
    __syncthreads();   // all reads of Hagg done before in-place overwrite
    ushort4 xp4[6];
    #pragma unroll
    for (int rt = 0; rt < 6; ++rt) {
        int r = bt0 + rt*16 + l16;
        xp4[rt] = *(const ushort4*)&Xp_nb[((size_t)n*BTq + r)*64 + w*16 + quad*4];
    }
    #pragma unroll
    for (int rt = 0; rt < 6; ++rt) {
        int r = bt0 + rt*16 + l16;
        ushort4 o;
        o.x = f2bf(gatef(bf2f(xp4[rt].x) + acc[rt][0]));
        o.y = f2bf(gatef(bf2f(xp4[rt].y) + acc[rt][1]));
        o.z = f2bf(gatef(bf2f(xp4[rt].z) + acc[rt][2]));
        o.w = f2bf(gatef(bf2f(xp4[rt].w) + acc[rt][3]));
        *(ushort4*)&Hout_nb[((size_t)n*BTq + r)*64 + w*16 + quad*4] = o;
    }
}

// GCN epilogue: out[b,d,n,t] = gcnB[d] + [Xp|H1|H2]@gcnW[d,:].
// grid 1824 = (b, n-tile 19, row-group 3).
__global__ void __launch_bounds__(256) kgcn(
    const unsigned short* __restrict__ Xp_nb, const unsigned short* __restrict__ H1_nb,
    const unsigned short* __restrict__ H2_nb, const float* __restrict__ gcnW,
    const float* __restrict__ gcnB, float* __restrict__ out)
{
    const int bid = blockIdx.x;
    const int b = bid / 57, rem = bid % 57;
    const int tile = rem / 3, rg = rem % 3;
    const int n0 = tile * 16;
    const int rows = (tile == 18) ? 144 : 192;
    const int r0base = rg * 64;
    const int tid = threadIdx.x;
    const int w = tid >> 6, lane = tid & 63, quad = lane >> 4, l16 = lane & 15;
    const int dcol = w*16 + l16;
    const float bias = gcnB[dcol];
    f4_t acc[4];
    #pragma unroll
    for (int rt = 0; rt < 4; ++rt) acc[rt] = (f4_t){0.f, 0.f, 0.f, 0.f};
    const unsigned short* bufs[3] = {Xp_nb, H1_nb, H2_nb};
    #pragma unroll
    for (int c = 0; c < 3; ++c) {
        const unsigned short* buf = bufs[c];
        const float* gwr = gcnW + (size_t)dcol*Fq + c*Dq;
        bf8_t v0 = pack8(ld4(gwr + quad*8),      ld4(gwr + quad*8 + 4));
        bf8_t v1 = pack8(ld4(gwr + 32 + quad*8), ld4(gwr + 36 + quad*8));
        #pragma unroll
        for (int rt = 0; rt < 4; ++rt) {
            int rr = r0base + rt*16;
            if (rr < rows) {
                int r = rr + l16;
                int nl = r / 12, t = r - nl*12;
                int n = n0 + nl; if (n > Nq-1) n = Nq-1;
                const unsigned short* row = buf + ((size_t)n*BTq + b*Tq + t)*64;
                bf8_t a0 = *(const bf8_t*)(row + quad*8);
                bf8_t a1 = *(const bf8_t*)(row + 32 + quad*8);
                acc[rt] = __builtin_amdgcn_mfma_f32_16x16x32_bf16(a0, v0, acc[rt], 0, 0, 0);
                acc[rt] = __builtin_amdgcn_mfma_f32_16x16x32_bf16(a1, v1, acc[rt], 0, 0, 0);
            }
        }
    }
    float* outd = out + (size_t)(b*Dq + dcol)*3600 + n0*12;
    #pragma unroll
    for (int rt = 0; rt < 4; ++rt) {
        int rr = r0base + rt*16;
        if (rr < rows) {
            int r0 = rr + quad*4;
            float4 o = make_float4(acc[rt][0] + bias, acc[rt][1] + bias,
                                   acc[rt][2] + bias, acc[rt][3] + bias);
            *(float4*)&outd[r0] = o;
        }
    }
}

extern "C" void kernel_launch(void* const* d_in, const int* in_sizes, int n_in,
                              void* d_out, int out_size, void* d_ws, size_t ws_size,
                              hipStream_t stream) {
    (void)in_sizes; (void)n_in; (void)out_size; (void)ws_size;
    const float* X    = (const float*)d_in[0];
    const float* te   = (const float*)d_in[1];
    const float* adjW = (const float*)d_in[2];
    const float* adjB = (const float*)d_in[3];
    const float* w1   = (const float*)d_in[4];
    const float* w2   = (const float*)d_in[5];
    const float* a1   = (const float*)d_in[6];
    const float* a2   = (const float*)d_in[7];
    const float* b1   = (const float*)d_in[8];
    const float* b2   = (const float*)d_in[9];
    const float* gW   = (const float*)d_in[10];
    const float* gB   = (const float*)d_in[11];
    float* out = (float*)d_out;

    char* ws = (char*)d_ws;
    unsigned*       ABt    = (unsigned*)      (ws);               //    409,600
    unsigned short* adjWb  = (unsigned short*)(ws + 409600);      //  +  40,960 =    450,560
    float*          adjBp  = (float*)         (ws + 450560);      //  +   1,280 =    451,840
    unsigned short* Wt     = (unsigned short*)(ws + 451840);      //  +2,457,600 =  2,909,440
    unsigned short* Xp_t   = (unsigned short*)(ws + 2909440);     // +15,728,640 = 18,638,080
    unsigned short* Xp_nb  = (unsigned short*)(ws + 18638080);    // +14,745,600 = 33,383,680
    unsigned short* Hagg   = (unsigned short*)(ws + 33383680);    // +14,745,600 = 48,129,280
    unsigned short* H1_nb  = (unsigned short*)(ws + 48129280);    // +14,745,600 = 62,874,880
    unsigned short* H1_t   = (unsigned short*)(ws + 62874880);    // +15,728,640 = 78,603,520
    unsigned short* teP    = (unsigned short*)(ws + 78603520);    // +14,745,600 = 93,349,120 B

    hipLaunchKernelGGL(kprep_all, dim3(1548), dim3(256), 0, stream,
                       a1, a2, b1, b2, w1, w2, adjW, adjB, X,
                       ABt, Wt, adjWb, adjBp, Xp_t, Xp_nb);
    // hop 1 (writes teP bf16 for hop 2)
    hipLaunchKernelGGL(HIP_KERNEL_NAME(kfuse_t<1>), dim3(1920), dim3(256), 0, stream,
                       te, teP, adjWb, adjBp, ABt, Xp_t, Hagg);
    hipLaunchKernelGGL(kmm,   dim3(1200), dim3(256), 0, stream, Hagg, Xp_nb, Wt, H1_nb);
    hipLaunchKernelGGL(ktr2,  dim3(384),  dim3(256), 0, stream, H1_nb, H1_t);
    // hop 2 (reads teP bf16)
    hipLaunchKernelGGL(HIP_KERNEL_NAME(kfuse_t<2>), dim3(1920), dim3(256), 0, stream,
                       te, teP, adjWb, adjBp, ABt, H1_t, Hagg);
    hipLaunchKernelGGL(kmm,   dim3(1200), dim3(256), 0, stream, Hagg, Xp_nb, Wt, Hagg); // in-place -> H2
    // gcn epilogue
    hipLaunchKernelGGL(kgcn,  dim3(1824), dim3(256), 0, stream, Xp_nb, H1_nb, Hagg, gW, gB, out);
}

// Round 4
// 289.749 us; speedup vs baseline: 1.3423x; 1.3423x over previous
//
#include <hip/hip_runtime.h>

#define Nq 300
#define Tq 12
#define Dq 64
#define Mq 16
#define BTq 384
#define DDq (Dq*Dq)      // 4096
#define Fq (Dq*3)        // 192
#define NP 320           // padded k-extent of transposed bf16 buffers

typedef short bf8_t __attribute__((ext_vector_type(8)));
typedef float f4_t  __attribute__((ext_vector_type(4)));

__device__ __forceinline__ unsigned short f2bf(float f) {
    unsigned u = __float_as_uint(f);
    u = (u + 0x7FFFu + ((u >> 16) & 1u)) >> 16;
    return (unsigned short)u;
}
__device__ __forceinline__ float bf2f(unsigned short u) {
    return __uint_as_float((unsigned)u << 16);
}
// v_cvt_pk_bf16_f32: dst[15:0]=bf16(lo), dst[31:16]=bf16(hi), RNE — identical
// bits to the f2bf bit-trick, 1 VALU instr instead of ~9 for a pair.
__device__ __forceinline__ unsigned cvtpk(float lo, float hi) {
    unsigned r;
    asm("v_cvt_pk_bf16_f32 %0, %1, %2" : "=v"(r) : "v"(lo), "v"(hi));
    return r;
}
__device__ __forceinline__ float4 ld4(const float* p) { return *(const float4*)p; }

__device__ __forceinline__ bf8_t pack8(float4 a, float4 b) {
    union { unsigned u[4]; bf8_t v; } q;
    q.u[0] = cvtpk(a.x, a.y); q.u[1] = cvtpk(a.z, a.w);
    q.u[2] = cvtpk(b.x, b.y); q.u[3] = cvtpk(b.z, b.w);
    return q.v;
}

// sigmoid(x)*tanh(x) == u*(u-1)/(u*u+1), u=e^x (exact algebra; 1 exp not 2)
__device__ __forceinline__ float gatef(float p) {
    float pc = fminf(fmaxf(p, -30.f), 30.f);
    float u = __expf(pc);
    return u * (u - 1.f) / (u * u + 1.f);
}

// ---- Merged front-end: 1548 blocks.
__global__ void __launch_bounds__(256) kprep_all(
    const float* __restrict__ a1, const float* __restrict__ a2,
    const float* __restrict__ b1, const float* __restrict__ b2,
    const float* __restrict__ w1, const float* __restrict__ w2,
    const float* __restrict__ adjW, const float* __restrict__ adjB,
    const float* __restrict__ X,
    unsigned* __restrict__ ABt, unsigned short* __restrict__ Wt,
    unsigned short* __restrict__ adjWb, float* __restrict__ adjBp,
    unsigned short* __restrict__ Xp_t, unsigned short* __restrict__ Xp_nb)
{
    __shared__ char smem[64 * 308 * 2];    // 39424 B union (only [32][308]*2B used by X path)
    const int vb = blockIdx.x;
    const int tid = threadIdx.x;

    if (vb < 400) {
        const int tile = vb;
        const int reg = tid & 3, lane = tid >> 2;
        const int nt = tile % 5;  int r1 = tile / 5;
        const int w  = r1 % 4;    int r2 = r1 / 4;
        const int c  = r2 % 5;    const int qi = r2 / 5;
        const int n = qi*80 + nt*16 + (lane & 15);
        const int k = c*64 + w*16 + (lane >> 4)*4 + reg;
        unsigned outv = 0u;
        if (n < Nq && k < Nq) {
            float sa = 0.f, sb = 0.f;
            #pragma unroll
            for (int m = 0; m < Mq; ++m) {
                sa = fmaf(a1[n*Mq+m], a2[m*Nq+k], sa);
                sb = fmaf(b1[n*Mq+m], b2[m*Nq+k], sb);
            }
            outv = cvtpk(sa, sb);   // low16 = alpha, high16 = beta (same as before)
        }
        ABt[tile*256 + tid] = outv;
    } else if (vb < 700) {
        float* sT = (float*)smem;          // [64][65]
        __shared__ float sw1[Mq];
        const int n = vb - 400;
        if (tid < Mq) sw1[tid] = w1[n*Mq + tid];
        __syncthreads();
        for (int i = tid; i < DDq; i += 256) {
            int k = i >> 6, d = i & 63;
            float s = 0.f;
            #pragma unroll
            for (int m = 0; m < Mq; ++m) s = fmaf(sw1[m], w2[m*DDq + i], s);
            sT[d*65 + k] = s;
        }
        __syncthreads();
        for (int i = tid; i < DDq; i += 256) {
            int d = i >> 6, k = i & 63;
            Wt[(size_t)n*DDq + i] = f2bf(sT[d*65 + k]);
        }
    } else if (vb < 780) {
        int e = (vb - 700) * 256 + tid;
        if (e < NP * 64) {
            int k = e >> 6, d = e & 63;
            adjWb[e] = (k < Nq) ? f2bf(adjW[k*Dq + d]) : (unsigned short)0;
        }
        if (e < NP) adjBp[e] = (e < Nq) ? adjB[e] : 0.f;
    } else {
        // X [b][d][n][t] -> Xp_t bf16 [bt][64][320] and Xp_nb bf16 [n][384][64]
        unsigned short* sT = (unsigned short*)smem;   // [32][308]
        const int bx = vb - 780;
        const int b = bx / 24, sub = bx % 24;
        const int tile = sub >> 1, half = sub & 1;
        const int n0 = tile * 25, d0 = half * 32;
        for (int i = tid; i < 32 * 75; i += 256) {
            int dl = i / 75, jq = i - dl*75, j = jq*4;
            float4 v = ld4(&X[(size_t)(b*64 + d0 + dl)*3600 + n0*12 + j]);
            *(uint2*)&sT[dl*308 + j] = make_uint2(cvtpk(v.x, v.y), cvtpk(v.z, v.w));
        }
        __syncthreads();
        for (int wi = tid; wi < 12 * 32 * 25; wi += 256) {
            int nl = wi % 25, rem = wi / 25;
            int dl = rem & 31, t = rem >> 5;
            Xp_t[((size_t)(b*Tq + t)*64 + d0 + dl)*NP + n0 + nl] = sT[dl*308 + nl*12 + t];
        }
        if (tile == 11) {
            for (int wi = tid; wi < 12 * 32 * 20; wi += 256) {
                int e = wi % 20, rem = wi / 20;
                int dl = rem & 31, t = rem >> 5;
                Xp_t[((size_t)(b*Tq + t)*64 + d0 + dl)*NP + 300 + e] = 0;
            }
        }
        for (int wi = tid; wi < 25 * 12 * 8; wi += 256) {
            int dg = wi & 7, rem = wi >> 3;
            int t = rem % 12, nl = rem / 12;
            ushort4 o;
            o.x = sT[(dg*4+0)*308 + nl*12 + t];
            o.y = sT[(dg*4+1)*308 + nl*12 + t];
            o.z = sT[(dg*4+2)*308 + nl*12 + t];
            o.w = sT[(dg*4+3)*308 + nl*12 + t];
            *(ushort4*)&Xp_nb[((size_t)(n0+nl)*BTq + b*Tq + t)*64 + d0 + dg*4] = o;
        }
    }
}

// bf16 transpose: H_nb [n][384][64] -> H_t [bt][64][320] (cols>=300 zero)
__global__ void __launch_bounds__(256) ktr2(const unsigned short* __restrict__ Hnb,
                                            unsigned short* __restrict__ Ht) {
    __shared__ unsigned short sT[64 * 308];
    const int bt = blockIdx.x;
    const int tid = threadIdx.x;
    for (int i = tid; i < 300 * 16; i += 256) {
        int nl = i >> 4, dg = i & 15;
        ushort4 v = *(const ushort4*)&Hnb[((size_t)nl*BTq + bt)*64 + dg*4];
        sT[(dg*4+0)*308 + nl] = v.x;
        sT[(dg*4+1)*308 + nl] = v.y;
        sT[(dg*4+2)*308 + nl] = v.z;
        sT[(dg*4+3)*308 + nl] = v.w;
    }
    __syncthreads();
    for (int wi = tid; wi < 64 * 80; wi += 256) {
        int kq = wi % 80, d = wi / 80;
        ushort4 o;
        int k = kq * 4;
        o.x = (k+0 < Nq) ? sT[d*308 + k+0] : (unsigned short)0;
        o.y = (k+1 < Nq) ? sT[d*308 + k+1] : (unsigned short)0;
        o.z = (k+2 < Nq) ? sT[d*308 + k+2] : (unsigned short)0;
        o.w = (k+3 < Nq) ? sT[d*308 + k+3] : (unsigned short)0;
        *(ushort4*)&Ht[((size_t)bt*64 + d)*NP + k] = o;
    }
}

// Fused A-recompute + aggregation (R2 proven structure: w-split, double-buffered
// LDS P^T, 1 barrier/c). HOP=1: read te fp32, write teP bf16. HOP=2: read teP.
// VALU cut: sin-chain + epilogue use v_cvt_pk_bf16_f32.
template<int HOP>
__global__ void __launch_bounds__(256) kfuse_t(
    const float* __restrict__ te,              // [B,N,T,D] fp32 (original input)
    unsigned short* __restrict__ teP,          // [bt][300][64] bf16 (HOP1 write / HOP2 read)
    const unsigned short* __restrict__ adjWb,  // [320][64]
    const float* __restrict__ adjBp,           // [320]
    const unsigned* __restrict__ ABt,          // tiled pairs
    const unsigned short* __restrict__ Hb_t,   // [bt][64][320]
    unsigned short* __restrict__ Hout_nb)      // [300][384][64]
{
    __shared__ unsigned short sPl[2][80 * 72];
    const int bt = blockIdx.x >> 2, qi = blockIdx.x & 3;
    const int b = bt / Tq, t = bt - b * Tq;
    const int nbase = qi * 80;
    const int tid = threadIdx.x;
    const int w = tid >> 6, lane = tid & 63, quad = lane >> 4, l16 = lane & 15;
    const int dcol = w*16 + l16;

    bf8_t tb0[5], tb1[5];
    #pragma unroll
    for (int nt = 0; nt < 5; ++nt) {
        int n = nbase + nt*16 + l16; if (n > Nq-1) n = Nq-1;
        if (HOP == 1) {
            const float* ter = te + (((size_t)b*Nq + n)*Tq + t)*Dq;
            tb0[nt] = pack8(ld4(ter + quad*8),      ld4(ter + quad*8 + 4));
            tb1[nt] = pack8(ld4(ter + 32 + quad*8), ld4(ter + 36 + quad*8));
            if (w == 0) {
                *(bf8_t*)&teP[((size_t)bt*Nq + n)*64 + quad*8] = tb0[nt];
                *(bf8_t*)&teP[((size_t)bt*Nq + n)*64 + 32 + quad*8] = tb1[nt];
            }
        } else {
            const unsigned short* tr = teP + ((size_t)bt*Nq + n)*64;
            tb0[nt] = *(const bf8_t*)(tr + quad*8);
            tb1[nt] = *(const bf8_t*)(tr + 32 + quad*8);
        }
    }
    f4_t accO[5];
    #pragma unroll
    for (int rt = 0; rt < 5; ++rt) accO[rt] = (f4_t){0.f, 0.f, 0.f, 0.f};

    const unsigned short* hr = Hb_t + ((size_t)bt*64 + dcol)*NP;
    bf8_t hv0 = *(const bf8_t*)(hr + quad*8);
    bf8_t hv1 = *(const bf8_t*)(hr + 32 + quad*8);

    for (int c = 0; c < 5; ++c) {
        const int cbase = c * 64;
        // prefetch next-c Hb fragments (consumed after next barrier)
        bf8_t nhv0, nhv1;
        if (c < 4) {
            nhv0 = *(const bf8_t*)(hr + cbase + 64 + quad*8);
            nhv1 = *(const bf8_t*)(hr + cbase + 96 + quad*8);
        }
        // hoisted ABt loads: all 5 in flight before the P-MFMA/sin chain
        const unsigned* abbase = ABt + ((((size_t)qi*5 + c)*4 + w)*5)*256 + lane*4;
        uint4 abv[5];
        #pragma unroll
        for (int nt = 0; nt < 5; ++nt) abv[nt] = *(const uint4*)(abbase + nt*256);
        const unsigned short* ar = adjWb + (cbase + w*16 + l16)*64;
        bf8_t ka0 = *(const bf8_t*)(ar + quad*8);
        bf8_t ka1 = *(const bf8_t*)(ar + 32 + quad*8);
        float4 bias4 = ld4(adjBp + cbase + w*16 + quad*4);
        unsigned short* sp = sPl[c & 1];
        #pragma unroll
        for (int nt = 0; nt < 5; ++nt) {
            f4_t p = {0.f, 0.f, 0.f, 0.f};
            p = __builtin_amdgcn_mfma_f32_16x16x32_bf16(ka0, tb0[nt], p, 0, 0, 0);
            p = __builtin_amdgcn_mfma_f32_16x16x32_bf16(ka1, tb1[nt], p, 0, 0, 0);
            uint4 ab = abv[nt];
            float s0 = fmaxf(fmaf(__uint_as_float(ab.x << 16), __sinf(p[0] + bias4.x),
                                  __uint_as_float(ab.x & 0xFFFF0000u)), 0.f);
            float s1 = fmaxf(fmaf(__uint_as_float(ab.y << 16), __sinf(p[1] + bias4.y),
                                  __uint_as_float(ab.y & 0xFFFF0000u)), 0.f);
            float s2 = fmaxf(fmaf(__uint_as_float(ab.z << 16), __sinf(p[2] + bias4.z),
                                  __uint_as_float(ab.z & 0xFFFF0000u)), 0.f);
            float s3 = fmaxf(fmaf(__uint_as_float(ab.w << 16), __sinf(p[3] + bias4.w),
                                  __uint_as_float(ab.w & 0xFFFF0000u)), 0.f);
            *(uint2*)&sp[(nt*16 + l16)*72 + w*16 + quad*4] =
                make_uint2(cvtpk(s0, s1), cvtpk(s2, s3));
        }
        __syncthreads();
        #pragma unroll
        for (int rt = 0; rt < 5; ++rt) {
            bf8_t p0 = *(const bf8_t*)&sp[(rt*16 + l16)*72 + quad*8];
            bf8_t p1 = *(const bf8_t*)&sp[(rt*16 + l16)*72 + 32 + quad*8];
            // swapped operands: D rows -> d (w*16+quad*4+reg), cols -> n (l16)
            accO[rt] = __builtin_amdgcn_mfma_f32_16x16x32_bf16(hv0, p0, accO[rt], 0, 0, 0);
            accO[rt] = __builtin_amdgcn_mfma_f32_16x16x32_bf16(hv1, p1, accO[rt], 0, 0, 0);
        }
        if (c < 4) { hv0 = nhv0; hv1 = nhv1; }
    }
    #pragma unroll
    for (int rt = 0; rt < 5; ++rt) {
        int n = nbase + rt*16 + l16;
        if (n < Nq) {
            *(uint2*)&Hout_nb[((size_t)n*BTq + bt)*64 + w*16 + quad*4] =
                make_uint2(cvtpk(accO[rt][0], accO[rt][1]),
                           cvtpk(accO[rt][2], accO[rt][3]));
        }
    }
}

// Per-node matmul + gate. grid 1200 = (n, bt-quarter of 96).
__global__ void __launch_bounds__(256) kmm(
    const unsigned short* __restrict__ Hagg_nb,  // [n][384][64]
    const unsigned short* __restrict__ Xp_nb,    // [n][384][64]
    const unsigned short* __restrict__ Wt,       // [n][64][64]
    unsigned short* __restrict__ Hout_nb)        // [n][384][64]
{
    const int n = blockIdx.x >> 2, qi = blockIdx.x & 3;
    const int bt0 = qi * 96;
    const int tid = threadIdx.x;
    const int w = tid >> 6, lane = tid & 63, quad = lane >> 4, l16 = lane & 15;
    const int dcol = w*16 + l16;
    const unsigned short* wn = Wt + (size_t)n * DDq + dcol*64;
    bf8_t v0 = *(const bf8_t*)(wn + quad*8);
    bf8_t v1 = *(const bf8_t*)(wn + 32 + quad*8);
    bf8_t a0[6], a1[6];
    #pragma unroll
    for (int rt = 0; rt < 6; ++rt) {
        int r = bt0 + rt*16 + l16;
        const unsigned short* row = Hagg_nb + ((size_t)n*BTq + r)*64;
        a0[rt] = *(const bf8_t*)(row + quad*8);
        a1[rt] = *(const bf8_t*)(row + 32 + quad*8);
    }
    f4_t acc[6];
    #pragma unroll
    for (int rt = 0; rt < 6; ++rt) acc[rt] = (f4_t){0.f, 0.f, 0.f, 0.f};
    #pragma unroll
    for (int rt = 0; rt < 6; ++rt) {
        acc[rt] = __builtin_amdgcn_mfma_f32_16x16x32_bf16(v0, a0[rt], acc[rt], 0, 0, 0);
        acc[rt] = __builtin_amdgcn_mfma_f32_16x16x32_bf16(v1, a1[rt], acc[rt], 0, 0, 0);
    }
    __syncthreads();   // all reads of Hagg done before in-place overwrite
    ushort4 xp4[6];
    #pragma unroll
    for (int rt = 0; rt < 6; ++rt) {
        int r = bt0 + rt*16 + l16;
        xp4[rt] = *(const ushort4*)&Xp_nb[((size_t)n*BTq + r)*64 + w*16 + quad*4];
    }
    #pragma unroll
    for (int rt = 0; rt < 6; ++rt) {
        int r = bt0 + rt*16 + l16;
        float g0 = gatef(bf2f(xp4[rt].x) + acc[rt][0]);
        float g1 = gatef(bf2f(xp4[rt].y) + acc[rt][1]);
        float g2 = gatef(bf2f(xp4[rt].z) + acc[rt][2]);
        float g3 = gatef(bf2f(xp4[rt].w) + acc[rt][3]);
        *(uint2*)&Hout_nb[((size_t)n*BTq + r)*64 + w*16 + quad*4] =
            make_uint2(cvtpk(g0, g1), cvtpk(g2, g3));
    }
}

// GCN epilogue: out[b,d,n,t] = gcnB[d] + [Xp|H1|H2]@gcnW[d,:].
// grid 1824 = (b, n-tile 19, row-group 3).
__global__ void __launch_bounds__(256) kgcn(
    const unsigned short* __restrict__ Xp_nb, const unsigned short* __restrict__ H1_nb,
    const unsigned short* __restrict__ H2_nb, const float* __restrict__ gcnW,
    const float* __restrict__ gcnB, float* __restrict__ out)
{
    const int bid = blockIdx.x;
    const int b = bid / 57, rem = bid % 57;
    const int tile = rem / 3, rg = rem % 3;
    const int n0 = tile * 16;
    const int rows = (tile == 18) ? 144 : 192;
    const int r0base = rg * 64;
    const int tid = threadIdx.x;
    const int w = tid >> 6, lane = tid & 63, quad = lane >> 4, l16 = lane & 15;
    const int dcol = w*16 + l16;
    const float bias = gcnB[dcol];
    f4_t acc[4];
    #pragma unroll
    for (int rt = 0; rt < 4; ++rt) acc[rt] = (f4_t){0.f, 0.f, 0.f, 0.f};
    const unsigned short* bufs[3] = {Xp_nb, H1_nb, H2_nb};
    #pragma unroll
    for (int c = 0; c < 3; ++c) {
        const unsigned short* buf = bufs[c];
        const float* gwr = gcnW + (size_t)dcol*Fq + c*Dq;
        bf8_t v0 = pack8(ld4(gwr + quad*8),      ld4(gwr + quad*8 + 4));
        bf8_t v1 = pack8(ld4(gwr + 32 + quad*8), ld4(gwr + 36 + quad*8));
        #pragma unroll
        for (int rt = 0; rt < 4; ++rt) {
            int rr = r0base + rt*16;
            if (rr < rows) {
                int r = rr + l16;
                int nl = r / 12, t = r - nl*12;
                int n = n0 + nl; if (n > Nq-1) n = Nq-1;
                const unsigned short* row = buf + ((size_t)n*BTq + b*Tq + t)*64;
                bf8_t a0 = *(const bf8_t*)(row + quad*8);
                bf8_t a1 = *(const bf8_t*)(row + 32 + quad*8);
                acc[rt] = __builtin_amdgcn_mfma_f32_16x16x32_bf16(a0, v0, acc[rt], 0, 0, 0);
                acc[rt] = __builtin_amdgcn_mfma_f32_16x16x32_bf16(a1, v1, acc[rt], 0, 0, 0);
            }
        }
    }
    float* outd = out + (size_t)(b*Dq + dcol)*3600 + n0*12;
    #pragma unroll
    for (int rt = 0; rt < 4; ++rt) {
        int rr = r0base + rt*16;
        if (rr < rows) {
            int r0 = rr + quad*4;
            float4 o = make_float4(acc[rt][0] + bias, acc[rt][1] + bias,
                                   acc[rt][2] + bias, acc[rt][3] + bias);
            *(float4*)&outd[r0] = o;
        }
    }
}

extern "C" void kernel_launch(void* const* d_in, const int* in_sizes, int n_in,
                              void* d_out, int out_size, void* d_ws, size_t ws_size,
                              hipStream_t stream) {
    (void)in_sizes; (void)n_in; (void)out_size; (void)ws_size;
    const float* X    = (const float*)d_in[0];
    const float* te   = (const float*)d_in[1];
    const float* adjW = (const float*)d_in[2];
    const float* adjB = (const float*)d_in[3];
    const float* w1   = (const float*)d_in[4];
    const float* w2   = (const float*)d_in[5];
    const float* a1   = (const float*)d_in[6];
    const float* a2   = (const float*)d_in[7];
    const float* b1   = (const float*)d_in[8];
    const float* b2   = (const float*)d_in[9];
    const float* gW   = (const float*)d_in[10];
    const float* gB   = (const float*)d_in[11];
    float* out = (float*)d_out;

    char* ws = (char*)d_ws;
    unsigned*       ABt    = (unsigned*)      (ws);               //    409,600
    unsigned short* adjWb  = (unsigned short*)(ws + 409600);      //  +  40,960 =    450,560
    float*          adjBp  = (float*)         (ws + 450560);      //  +   1,280 =    451,840
    unsigned short* Wt     = (unsigned short*)(ws + 451840);      //  +2,457,600 =  2,909,440
    unsigned short* Xp_t   = (unsigned short*)(ws + 2909440);     // +15,728,640 = 18,638,080
    unsigned short* Xp_nb  = (unsigned short*)(ws + 18638080);    // +14,745,600 = 33,383,680
    unsigned short* Hagg   = (unsigned short*)(ws + 33383680);    // +14,745,600 = 48,129,280
    unsigned short* H1_nb  = (unsigned short*)(ws + 48129280);    // +14,745,600 = 62,874,880
    unsigned short* H1_t   = (unsigned short*)(ws + 62874880);    // +15,728,640 = 78,603,520
    unsigned short* teP    = (unsigned short*)(ws + 78603520);    // +14,745,600 = 93,349,120 B

    hipLaunchKernelGGL(kprep_all, dim3(1548), dim3(256), 0, stream,
                       a1, a2, b1, b2, w1, w2, adjW, adjB, X,
                       ABt, Wt, adjWb, adjBp, Xp_t, Xp_nb);
    // hop 1 (writes teP bf16 for hop 2)
    hipLaunchKernelGGL(HIP_KERNEL_NAME(kfuse_t<1>), dim3(1536), dim3(256), 0, stream,
                       te, teP, adjWb, adjBp, ABt, Xp_t, Hagg);
    hipLaunchKernelGGL(kmm,   dim3(1200), dim3(256), 0, stream, Hagg, Xp_nb, Wt, H1_nb);
    hipLaunchKernelGGL(ktr2,  dim3(384),  dim3(256), 0, stream, H1_nb, H1_t);
    // hop 2 (reads teP bf16)
    hipLaunchKernelGGL(HIP_KERNEL_NAME(kfuse_t<2>), dim3(1536), dim3(256), 0, stream,
                       te, teP, adjWb, adjBp, ABt, H1_t, Hagg);
    hipLaunchKernelGGL(kmm,   dim3(1200), dim3(256), 0, stream, Hagg, Xp_nb, Wt, Hagg); // in-place -> H2
    // gcn epilogue
    hipLaunchKernelGGL(kgcn,  dim3(1824), dim3(256), 0, stream, Xp_nb, H1_nb, Hagg, gW, gB, out);
}

// Round 5
// 288.873 us; speedup vs baseline: 1.3464x; 1.0030x over previous
//
#include <hip/hip_runtime.h>

#define Nq 300
#define Tq 12
#define Dq 64
#define Mq 16
#define BTq 384
#define DDq (Dq*Dq)      // 4096
#define Fq (Dq*3)        // 192
#define NP 320           // padded k-extent of transposed bf16 buffers

typedef short bf8_t __attribute__((ext_vector_type(8)));
typedef float f4_t  __attribute__((ext_vector_type(4)));

__device__ __forceinline__ unsigned short f2bf(float f) {
    unsigned u = __float_as_uint(f);
    u = (u + 0x7FFFu + ((u >> 16) & 1u)) >> 16;
    return (unsigned short)u;
}
__device__ __forceinline__ float bf2f(unsigned short u) {
    return __uint_as_float((unsigned)u << 16);
}
// v_cvt_pk_bf16_f32: dst[15:0]=bf16(lo), dst[31:16]=bf16(hi), RNE — identical
// bits to the f2bf bit-trick, 1 VALU instr for a pair.
__device__ __forceinline__ unsigned cvtpk(float lo, float hi) {
    unsigned r;
    asm("v_cvt_pk_bf16_f32 %0, %1, %2" : "=v"(r) : "v"(lo), "v"(hi));
    return r;
}
__device__ __forceinline__ float4 ld4(const float* p) { return *(const float4*)p; }

__device__ __forceinline__ bf8_t pack8(float4 a, float4 b) {
    union { unsigned u[4]; bf8_t v; } q;
    q.u[0] = cvtpk(a.x, a.y); q.u[1] = cvtpk(a.z, a.w);
    q.u[2] = cvtpk(b.x, b.y); q.u[3] = cvtpk(b.z, b.w);
    return q.v;
}

// sigmoid(x)*tanh(x) == u*(u-1)/(u*u+1), u=e^x (exact algebra; 1 exp not 2)
__device__ __forceinline__ float gatef(float p) {
    float pc = fminf(fmaxf(p, -30.f), 30.f);
    float u = __expf(pc);
    return u * (u - 1.f) / (u * u + 1.f);
}

// ---- Merged front-end: 1548 blocks.
__global__ void __launch_bounds__(256) kprep_all(
    const float* __restrict__ a1, const float* __restrict__ a2,
    const float* __restrict__ b1, const float* __restrict__ b2,
    const float* __restrict__ w1, const float* __restrict__ w2,
    const float* __restrict__ adjW, const float* __restrict__ adjB,
    const float* __restrict__ X,
    unsigned* __restrict__ ABt, unsigned short* __restrict__ Wt,
    unsigned short* __restrict__ adjWb, float* __restrict__ adjBp,
    unsigned short* __restrict__ Xp_t, unsigned short* __restrict__ Xp_nb)
{
    __shared__ char smem[64 * 308 * 2];    // 39424 B union (only [32][308]*2B used by X path)
    const int vb = blockIdx.x;
    const int tid = threadIdx.x;

    if (vb < 400) {
        const int tile = vb;
        const int reg = tid & 3, lane = tid >> 2;
        const int nt = tile % 5;  int r1 = tile / 5;
        const int w  = r1 % 4;    int r2 = r1 / 4;
        const int c  = r2 % 5;    const int qi = r2 / 5;
        const int n = qi*80 + nt*16 + (lane & 15);
        const int k = c*64 + w*16 + (lane >> 4)*4 + reg;
        unsigned outv = 0u;
        if (n < Nq && k < Nq) {
            float sa = 0.f, sb = 0.f;
            #pragma unroll
            for (int m = 0; m < Mq; ++m) {
                sa = fmaf(a1[n*Mq+m], a2[m*Nq+k], sa);
                sb = fmaf(b1[n*Mq+m], b2[m*Nq+k], sb);
            }
            outv = cvtpk(sa, sb);   // low16 = alpha, high16 = beta
        }
        ABt[tile*256 + tid] = outv;
    } else if (vb < 700) {
        float* sT = (float*)smem;          // [64][65]
        __shared__ float sw1[Mq];
        const int n = vb - 400;
        if (tid < Mq) sw1[tid] = w1[n*Mq + tid];
        __syncthreads();
        for (int i = tid; i < DDq; i += 256) {
            int k = i >> 6, d = i & 63;
            float s = 0.f;
            #pragma unroll
            for (int m = 0; m < Mq; ++m) s = fmaf(sw1[m], w2[m*DDq + i], s);
            sT[d*65 + k] = s;
        }
        __syncthreads();
        for (int i = tid; i < DDq; i += 256) {
            int d = i >> 6, k = i & 63;
            Wt[(size_t)n*DDq + i] = f2bf(sT[d*65 + k]);
        }
    } else if (vb < 780) {
        int e = (vb - 700) * 256 + tid;
        if (e < NP * 64) {
            int k = e >> 6, d = e & 63;
            adjWb[e] = (k < Nq) ? f2bf(adjW[k*Dq + d]) : (unsigned short)0;
        }
        if (e < NP) adjBp[e] = (e < Nq) ? adjB[e] : 0.f;
    } else {
        // X [b][d][n][t] -> Xp_t bf16 [bt][64][320] and Xp_nb bf16 [n][384][64]
        unsigned short* sT = (unsigned short*)smem;   // [32][308]
        const int bx = vb - 780;
        const int b = bx / 24, sub = bx % 24;
        const int tile = sub >> 1, half = sub & 1;
        const int n0 = tile * 25, d0 = half * 32;
        for (int i = tid; i < 32 * 75; i += 256) {
            int dl = i / 75, jq = i - dl*75, j = jq*4;
            float4 v = ld4(&X[(size_t)(b*64 + d0 + dl)*3600 + n0*12 + j]);
            *(uint2*)&sT[dl*308 + j] = make_uint2(cvtpk(v.x, v.y), cvtpk(v.z, v.w));
        }
        __syncthreads();
        for (int wi = tid; wi < 12 * 32 * 25; wi += 256) {
            int nl = wi % 25, rem = wi / 25;
            int dl = rem & 31, t = rem >> 5;
            Xp_t[((size_t)(b*Tq + t)*64 + d0 + dl)*NP + n0 + nl] = sT[dl*308 + nl*12 + t];
        }
        if (tile == 11) {
            for (int wi = tid; wi < 12 * 32 * 20; wi += 256) {
                int e = wi % 20, rem = wi / 20;
                int dl = rem & 31, t = rem >> 5;
                Xp_t[((size_t)(b*Tq + t)*64 + d0 + dl)*NP + 300 + e] = 0;
            }
        }
        for (int wi = tid; wi < 25 * 12 * 8; wi += 256) {
            int dg = wi & 7, rem = wi >> 3;
            int t = rem % 12, nl = rem / 12;
            ushort4 o;
            o.x = sT[(dg*4+0)*308 + nl*12 + t];
            o.y = sT[(dg*4+1)*308 + nl*12 + t];
            o.z = sT[(dg*4+2)*308 + nl*12 + t];
            o.w = sT[(dg*4+3)*308 + nl*12 + t];
            *(ushort4*)&Xp_nb[((size_t)(n0+nl)*BTq + b*Tq + t)*64 + d0 + dg*4] = o;
        }
    }
}

// bf16 transpose: H_nb [n][384][64] -> H_t [bt][64][320] (cols>=300 zero)
__global__ void __launch_bounds__(256) ktr2(const unsigned short* __restrict__ Hnb,
                                            unsigned short* __restrict__ Ht) {
    __shared__ unsigned short sT[64 * 308];
    const int bt = blockIdx.x;
    const int tid = threadIdx.x;
    for (int i = tid; i < 300 * 8; i += 256) {
        int nl = i >> 3, dg = i & 7;
        bf8_t v = *(const bf8_t*)&Hnb[((size_t)nl*BTq + bt)*64 + dg*8];
        #pragma unroll
        for (int k = 0; k < 8; ++k)
            sT[(dg*8+k)*308 + nl] = (unsigned short)v[k];
    }
    __syncthreads();
    for (int wi = tid; wi < 64 * 80; wi += 256) {
        int kq = wi % 80, d = wi / 80;
        ushort4 o;
        int k = kq * 4;
        o.x = (k+0 < Nq) ? sT[d*308 + k+0] : (unsigned short)0;
        o.y = (k+1 < Nq) ? sT[d*308 + k+1] : (unsigned short)0;
        o.z = (k+2 < Nq) ? sT[d*308 + k+2] : (unsigned short)0;
        o.w = (k+3 < Nq) ? sT[d*308 + k+3] : (unsigned short)0;
        *(ushort4*)&Ht[((size_t)bt*64 + d)*NP + k] = o;
    }
}

// Fused A-recompute + aggregation. Transaction-dense version:
//  - te/teP staged into LDS with lane-contiguous cooperative loads
//  - output staged through LDS, written as row-dense 16 B/lane streams
//  - single P buffer (22.4 KB total LDS -> 7 blocks/CU), 2 barriers per c
template<int HOP>
__global__ void __launch_bounds__(256) kfuse_t(
    const float* __restrict__ te,              // [B,N,T,D] fp32 (original input)
    unsigned short* __restrict__ teP,          // [bt][300][64] bf16 (HOP1 write / HOP2 read)
    const unsigned short* __restrict__ adjWb,  // [320][64]
    const float* __restrict__ adjBp,           // [320]
    const unsigned* __restrict__ ABt,          // tiled pairs
    const unsigned short* __restrict__ Hb_t,   // [bt][64][320]
    unsigned short* __restrict__ Hout_nb)      // [300][384][64]
{
    __shared__ unsigned short sP[80 * 72];     // 11520 B, P^T tile
    __shared__ unsigned short sT[80 * 68];     // 10880 B, te stage / out stage (aliased)
    const int bt = blockIdx.x >> 2, qi = blockIdx.x & 3;
    const int b = bt / Tq, t = bt - b * Tq;
    const int nbase = qi * 80;
    const int tid = threadIdx.x;
    const int w = tid >> 6, lane = tid & 63, quad = lane >> 4, l16 = lane & 15;
    const int dcol = w*16 + l16;
    const int nrows = (Nq - nbase < 80) ? (Nq - nbase) : 80;

    // ---- stage te (hop1, fp32->bf16) or teP (hop2) into sT, lane-contiguous
    if (HOP == 1) {
        #pragma unroll
        for (int r = 0; r < 5; ++r) {
            int row = r*16 + (tid >> 4);          // 0..79
            int col = (tid & 15) * 4;             // float idx, 16 B span per lane
            int n = nbase + row; if (n > Nq-1) n = Nq-1;
            float4 v = ld4(te + (((size_t)b*Nq + n)*Tq + t)*Dq + col);
            *(uint2*)&sT[row*68 + col] = make_uint2(cvtpk(v.x, v.y), cvtpk(v.z, v.w));
        }
    } else {
        for (int idx = tid; idx < 80*8; idx += 256) {
            int row = idx >> 3, cg = idx & 7;
            int n = nbase + row; if (n > Nq-1) n = Nq-1;
            *(bf8_t*)&sT[row*68 + cg*8] =
                *(const bf8_t*)&teP[((size_t)bt*Nq + n)*64 + cg*8];
        }
    }
    __syncthreads();
    if (HOP == 1) {
        // stream teP out of LDS (contiguous 16 B/lane)
        for (int idx = tid; idx < nrows*8; idx += 256) {
            int row = idx >> 3, cg = idx & 7;
            *(bf8_t*)&teP[((size_t)bt*Nq + nbase + row)*64 + cg*8] =
                *(const bf8_t*)&sT[row*68 + cg*8];
        }
    }
    // te fragments from LDS (B-op rows d=quad*8+j, col n=l16, per nt)
    bf8_t tb0[5], tb1[5];
    #pragma unroll
    for (int nt = 0; nt < 5; ++nt) {
        const unsigned short* tr = &sT[(nt*16 + l16)*68];
        tb0[nt] = *(const bf8_t*)(tr + quad*8);
        tb1[nt] = *(const bf8_t*)(tr + 32 + quad*8);
    }

    f4_t accO[5];
    #pragma unroll
    for (int rt = 0; rt < 5; ++rt) accO[rt] = (f4_t){0.f, 0.f, 0.f, 0.f};

    const unsigned short* hr = Hb_t + ((size_t)bt*64 + dcol)*NP;

    for (int c = 0; c < 5; ++c) {
        const int cbase = c * 64;
        // issue this c's loads before the WAR barrier (latency hides under it)
        const unsigned* abbase = ABt + ((((size_t)qi*5 + c)*4 + w)*5)*256 + lane*4;
        uint4 abv[5];
        #pragma unroll
        for (int nt = 0; nt < 5; ++nt) abv[nt] = *(const uint4*)(abbase + nt*256);
        const unsigned short* ar = adjWb + (cbase + w*16 + l16)*64;
        bf8_t ka0 = *(const bf8_t*)(ar + quad*8);
        bf8_t ka1 = *(const bf8_t*)(ar + 32 + quad*8);
        float4 bias4 = ld4(adjBp + cbase + w*16 + quad*4);
        bf8_t hv0 = *(const bf8_t*)(hr + cbase + quad*8);
        bf8_t hv1 = *(const bf8_t*)(hr + cbase + 32 + quad*8);

        if (c > 0) __syncthreads();   // prior consume of sP complete
        #pragma unroll
        for (int nt = 0; nt < 5; ++nt) {
            f4_t p = {0.f, 0.f, 0.f, 0.f};
            p = __builtin_amdgcn_mfma_f32_16x16x32_bf16(ka0, tb0[nt], p, 0, 0, 0);
            p = __builtin_amdgcn_mfma_f32_16x16x32_bf16(ka1, tb1[nt], p, 0, 0, 0);
            uint4 ab = abv[nt];
            float s0 = fmaxf(fmaf(__uint_as_float(ab.x << 16), __sinf(p[0] + bias4.x),
                                  __uint_as_float(ab.x & 0xFFFF0000u)), 0.f);
            float s1 = fmaxf(fmaf(__uint_as_float(ab.y << 16), __sinf(p[1] + bias4.y),
                                  __uint_as_float(ab.y & 0xFFFF0000u)), 0.f);
            float s2 = fmaxf(fmaf(__uint_as_float(ab.z << 16), __sinf(p[2] + bias4.z),
                                  __uint_as_float(ab.z & 0xFFFF0000u)), 0.f);
            float s3 = fmaxf(fmaf(__uint_as_float(ab.w << 16), __sinf(p[3] + bias4.w),
                                  __uint_as_float(ab.w & 0xFFFF0000u)), 0.f);
            *(uint2*)&sP[(nt*16 + l16)*72 + w*16 + quad*4] =
                make_uint2(cvtpk(s0, s1), cvtpk(s2, s3));
        }
        __syncthreads();
        #pragma unroll
        for (int rt = 0; rt < 5; ++rt) {
            bf8_t p0 = *(const bf8_t*)&sP[(rt*16 + l16)*72 + quad*8];
            bf8_t p1 = *(const bf8_t*)&sP[(rt*16 + l16)*72 + 32 + quad*8];
            // swapped operands: D rows -> d (w*16+quad*4+reg), cols -> n (l16)
            accO[rt] = __builtin_amdgcn_mfma_f32_16x16x32_bf16(hv0, p0, accO[rt], 0, 0, 0);
            accO[rt] = __builtin_amdgcn_mfma_f32_16x16x32_bf16(hv1, p1, accO[rt], 0, 0, 0);
        }
    }
    // ---- stage output to sT (aliased; te reads long done), then stream out
    #pragma unroll
    for (int rt = 0; rt < 5; ++rt) {
        *(uint2*)&sT[(rt*16 + l16)*68 + w*16 + quad*4] =
            make_uint2(cvtpk(accO[rt][0], accO[rt][1]),
                       cvtpk(accO[rt][2], accO[rt][3]));
    }
    __syncthreads();
    for (int idx = tid; idx < nrows*8; idx += 256) {
        int row = idx >> 3, cg = idx & 7;
        *(bf8_t*)&Hout_nb[((size_t)(nbase + row)*BTq + bt)*64 + cg*8] =
            *(const bf8_t*)&sT[row*68 + cg*8];
    }
}

// Per-node matmul + gate. grid 1200 = (n, bt-quarter of 96).
__global__ void __launch_bounds__(256) kmm(
    const unsigned short* __restrict__ Hagg_nb,  // [n][384][64]
    const unsigned short* __restrict__ Xp_nb,    // [n][384][64]
    const unsigned short* __restrict__ Wt,       // [n][64][64]
    unsigned short* __restrict__ Hout_nb)        // [n][384][64]
{
    const int n = blockIdx.x >> 2, qi = blockIdx.x & 3;
    const int bt0 = qi * 96;
    const int tid = threadIdx.x;
    const int w = tid >> 6, lane = tid & 63, quad = lane >> 4, l16 = lane & 15;
    const int dcol = w*16 + l16;
    const unsigned short* wn = Wt + (size_t)n * DDq + dcol*64;
    bf8_t v0 = *(const bf8_t*)(wn + quad*8);
    bf8_t v1 = *(const bf8_t*)(wn + 32 + quad*8);
    bf8_t a0[6], a1[6];
    #pragma unroll
    for (int rt = 0; rt < 6; ++rt) {
        int r = bt0 + rt*16 + l16;
        const unsigned short* row = Hagg_nb + ((size_t)n*BTq + r)*64;
        a0[rt] = *(const bf8_t*)(row + quad*8);
        a1[rt] = *(const bf8_t*)(row + 32 + quad*8);
    }
    f4_t acc[6];
    #pragma unroll
    for (int rt = 0; rt < 6; ++rt) acc[rt] = (f4_t){0.f, 0.f, 0.f, 0.f};
    #pragma unroll
    for (int rt = 0; rt < 6; ++rt) {
        acc[rt] = __builtin_amdgcn_mfma_f32_16x16x32_bf16(v0, a0[rt], acc[rt], 0, 0, 0);
        acc[rt] = __builtin_amdgcn_mfma_f32_16x16x32_bf16(v1, a1[rt], acc[rt], 0, 0, 0);
    }
    __syncthreads();   // all reads of Hagg done before in-place overwrite
    ushort4 xp4[6];
    #pragma unroll
    for (int rt = 0; rt < 6; ++rt) {
        int r = bt0 + rt*16 + l16;
        xp4[rt] = *(const ushort4*)&Xp_nb[((size_t)n*BTq + r)*64 + w*16 + quad*4];
    }
    #pragma unroll
    for (int rt = 0; rt < 6; ++rt) {
        int r = bt0 + rt*16 + l16;
        float g0 = gatef(bf2f(xp4[rt].x) + acc[rt][0]);
        float g1 = gatef(bf2f(xp4[rt].y) + acc[rt][1]);
        float g2 = gatef(bf2f(xp4[rt].z) + acc[rt][2]);
        float g3 = gatef(bf2f(xp4[rt].w) + acc[rt][3]);
        *(uint2*)&Hout_nb[((size_t)n*BTq + r)*64 + w*16 + quad*4] =
            make_uint2(cvtpk(g0, g1), cvtpk(g2, g3));
    }
}

// GCN epilogue: out[b,d,n,t] = gcnB[d] + [Xp|H1|H2]@gcnW[d,:].
// grid 1824 = (b, n-tile 19, row-group 3).
__global__ void __launch_bounds__(256) kgcn(
    const unsigned short* __restrict__ Xp_nb, const unsigned short* __restrict__ H1_nb,
    const unsigned short* __restrict__ H2_nb, const float* __restrict__ gcnW,
    const float* __restrict__ gcnB, float* __restrict__ out)
{
    const int bid = blockIdx.x;
    const int b = bid / 57, rem = bid % 57;
    const int tile = rem / 3, rg = rem % 3;
    const int n0 = tile * 16;
    const int rows = (tile == 18) ? 144 : 192;
    const int r0base = rg * 64;
    const int tid = threadIdx.x;
    const int w = tid >> 6, lane = tid & 63, quad = lane >> 4, l16 = lane & 15;
    const int dcol = w*16 + l16;
    const float bias = gcnB[dcol];
    f4_t acc[4];
    #pragma unroll
    for (int rt = 0; rt < 4; ++rt) acc[rt] = (f4_t){0.f, 0.f, 0.f, 0.f};
    const unsigned short* bufs[3] = {Xp_nb, H1_nb, H2_nb};
    #pragma unroll
    for (int c = 0; c < 3; ++c) {
        const unsigned short* buf = bufs[c];
        const float* gwr = gcnW + (size_t)dcol*Fq + c*Dq;
        bf8_t v0 = pack8(ld4(gwr + quad*8),      ld4(gwr + quad*8 + 4));
        bf8_t v1 = pack8(ld4(gwr + 32 + quad*8), ld4(gwr + 36 + quad*8));
        #pragma unroll
        for (int rt = 0; rt < 4; ++rt) {
            int rr = r0base + rt*16;
            if (rr < rows) {
                int r = rr + l16;
                int nl = r / 12, t = r - nl*12;
                int n = n0 + nl; if (n > Nq-1) n = Nq-1;
                const unsigned short* row = buf + ((size_t)n*BTq + b*Tq + t)*64;
                bf8_t a0 = *(const bf8_t*)(row + quad*8);
                bf8_t a1 = *(const bf8_t*)(row + 32 + quad*8);
                acc[rt] = __builtin_amdgcn_mfma_f32_16x16x32_bf16(a0, v0, acc[rt], 0, 0, 0);
                acc[rt] = __builtin_amdgcn_mfma_f32_16x16x32_bf16(a1, v1, acc[rt], 0, 0, 0);
            }
        }
    }
    float* outd = out + (size_t)(b*Dq + dcol)*3600 + n0*12;
    #pragma unroll
    for (int rt = 0; rt < 4; ++rt) {
        int rr = r0base + rt*16;
        if (rr < rows) {
            int r0 = rr + quad*4;
            float4 o = make_float4(acc[rt][0] + bias, acc[rt][1] + bias,
                                   acc[rt][2] + bias, acc[rt][3] + bias);
            *(float4*)&outd[r0] = o;
        }
    }
}

extern "C" void kernel_launch(void* const* d_in, const int* in_sizes, int n_in,
                              void* d_out, int out_size, void* d_ws, size_t ws_size,
                              hipStream_t stream) {
    (void)in_sizes; (void)n_in; (void)out_size; (void)ws_size;
    const float* X    = (const float*)d_in[0];
    const float* te   = (const float*)d_in[1];
    const float* adjW = (const float*)d_in[2];
    const float* adjB = (const float*)d_in[3];
    const float* w1   = (const float*)d_in[4];
    const float* w2   = (const float*)d_in[5];
    const float* a1   = (const float*)d_in[6];
    const float* a2   = (const float*)d_in[7];
    const float* b1   = (const float*)d_in[8];
    const float* b2   = (const float*)d_in[9];
    const float* gW   = (const float*)d_in[10];
    const float* gB   = (const float*)d_in[11];
    float* out = (float*)d_out;

    char* ws = (char*)d_ws;
    unsigned*       ABt    = (unsigned*)      (ws);               //    409,600
    unsigned short* adjWb  = (unsigned short*)(ws + 409600);      //  +  40,960 =    450,560
    float*          adjBp  = (float*)         (ws + 450560);      //  +   1,280 =    451,840
    unsigned short* Wt     = (unsigned short*)(ws + 451840);      //  +2,457,600 =  2,909,440
    unsigned short* Xp_t   = (unsigned short*)(ws + 2909440);     // +15,728,640 = 18,638,080
    unsigned short* Xp_nb  = (unsigned short*)(ws + 18638080);    // +14,745,600 = 33,383,680
    unsigned short* Hagg   = (unsigned short*)(ws + 33383680);    // +14,745,600 = 48,129,280
    unsigned short* H1_nb  = (unsigned short*)(ws + 48129280);    // +14,745,600 = 62,874,880
    unsigned short* H1_t   = (unsigned short*)(ws + 62874880);    // +15,728,640 = 78,603,520
    unsigned short* teP    = (unsigned short*)(ws + 78603520);    // +14,745,600 = 93,349,120 B

    hipLaunchKernelGGL(kprep_all, dim3(1548), dim3(256), 0, stream,
                       a1, a2, b1, b2, w1, w2, adjW, adjB, X,
                       ABt, Wt, adjWb, adjBp, Xp_t, Xp_nb);
    // hop 1 (writes teP bf16 for hop 2)
    hipLaunchKernelGGL(HIP_KERNEL_NAME(kfuse_t<1>), dim3(1536), dim3(256), 0, stream,
                       te, teP, adjWb, adjBp, ABt, Xp_t, Hagg);
    hipLaunchKernelGGL(kmm,   dim3(1200), dim3(256), 0, stream, Hagg, Xp_nb, Wt, H1_nb);
    hipLaunchKernelGGL(ktr2,  dim3(384),  dim3(256), 0, stream, H1_nb, H1_t);
    // hop 2 (reads teP bf16)
    hipLaunchKernelGGL(HIP_KERNEL_NAME(kfuse_t<2>), dim3(1536), dim3(256), 0, stream,
                       te, teP, adjWb, adjBp, ABt, H1_t, Hagg);
    hipLaunchKernelGGL(kmm,   dim3(1200), dim3(256), 0, stream, Hagg, Xp_nb, Wt, Hagg); // in-place -> H2
    // gcn epilogue
    hipLaunchKernelGGL(kgcn,  dim3(1824), dim3(256), 0, stream, Xp_nb, H1_nb, Hagg, gW, gB, out);
}

// Round 6
// 284.986 us; speedup vs baseline: 1.3647x; 1.0136x over previous
//
#include <hip/hip_runtime.h>

#define Nq 300
#define Tq 12
#define Dq 64
#define Mq 16
#define BTq 384
#define DDq (Dq*Dq)      // 4096
#define Fq (Dq*3)        // 192
#define NP 320           // padded k-extent of transposed bf16 buffers

typedef short bf8_t __attribute__((ext_vector_type(8)));
typedef float f4_t  __attribute__((ext_vector_type(4)));

__device__ __forceinline__ unsigned short f2bf(float f) {
    unsigned u = __float_as_uint(f);
    u = (u + 0x7FFFu + ((u >> 16) & 1u)) >> 16;
    return (unsigned short)u;
}
__device__ __forceinline__ float bf2f(unsigned short u) {
    return __uint_as_float((unsigned)u << 16);
}
// v_cvt_pk_bf16_f32: dst[15:0]=bf16(lo), dst[31:16]=bf16(hi), RNE — identical
// bits to the f2bf bit-trick, 1 VALU instr for a pair.
__device__ __forceinline__ unsigned cvtpk(float lo, float hi) {
    unsigned r;
    asm("v_cvt_pk_bf16_f32 %0, %1, %2" : "=v"(r) : "v"(lo), "v"(hi));
    return r;
}
__device__ __forceinline__ float4 ld4(const float* p) { return *(const float4*)p; }

__device__ __forceinline__ bf8_t pack8(float4 a, float4 b) {
    union { unsigned u[4]; bf8_t v; } q;
    q.u[0] = cvtpk(a.x, a.y); q.u[1] = cvtpk(a.z, a.w);
    q.u[2] = cvtpk(b.x, b.y); q.u[3] = cvtpk(b.z, b.w);
    return q.v;
}

// sigmoid(x)*tanh(x) == u*(u-1)/(u*u+1), u=e^x (exact algebra; 1 exp not 2)
__device__ __forceinline__ float gatef(float p) {
    float pc = fminf(fmaxf(p, -30.f), 30.f);
    float u = __expf(pc);
    return u * (u - 1.f) / (u * u + 1.f);
}

// ---- Merged front-end: 1580 blocks.
//  [0,400)    ABt tiles
//  [400,700)  Wt per-node weights
//  [700,780)  adjWb/adjBp padding
//  [780,1580) X transpose: 12-n tiles, full d, all-vector stores
__global__ void __launch_bounds__(256) kprep_all(
    const float* __restrict__ a1, const float* __restrict__ a2,
    const float* __restrict__ b1, const float* __restrict__ b2,
    const float* __restrict__ w1, const float* __restrict__ w2,
    const float* __restrict__ adjW, const float* __restrict__ adjB,
    const float* __restrict__ X,
    unsigned* __restrict__ ABt, unsigned short* __restrict__ Wt,
    unsigned short* __restrict__ adjWb, float* __restrict__ adjBp,
    unsigned short* __restrict__ Xp_t, unsigned short* __restrict__ Xp_nb)
{
    __shared__ __align__(16) char smem[64 * 308 * 2];    // 39424 B union
    const int vb = blockIdx.x;
    const int tid = threadIdx.x;

    if (vb < 400) {
        const int tile = vb;
        const int reg = tid & 3, lane = tid >> 2;
        const int nt = tile % 5;  int r1 = tile / 5;
        const int w  = r1 % 4;    int r2 = r1 / 4;
        const int c  = r2 % 5;    const int qi = r2 / 5;
        const int n = qi*80 + nt*16 + (lane & 15);
        const int k = c*64 + w*16 + (lane >> 4)*4 + reg;
        unsigned outv = 0u;
        if (n < Nq && k < Nq) {
            float sa = 0.f, sb = 0.f;
            #pragma unroll
            for (int m = 0; m < Mq; ++m) {
                sa = fmaf(a1[n*Mq+m], a2[m*Nq+k], sa);
                sb = fmaf(b1[n*Mq+m], b2[m*Nq+k], sb);
            }
            outv = cvtpk(sa, sb);   // low16 = alpha, high16 = beta
        }
        ABt[tile*256 + tid] = outv;
    } else if (vb < 700) {
        float* sT = (float*)smem;          // [64][65]
        __shared__ float sw1[Mq];
        const int n = vb - 400;
        if (tid < Mq) sw1[tid] = w1[n*Mq + tid];
        __syncthreads();
        for (int i = tid; i < DDq; i += 256) {
            int k = i >> 6, d = i & 63;
            float s = 0.f;
            #pragma unroll
            for (int m = 0; m < Mq; ++m) s = fmaf(sw1[m], w2[m*DDq + i], s);
            sT[d*65 + k] = s;
        }
        __syncthreads();
        for (int i = tid; i < DDq; i += 256) {
            int d = i >> 6, k = i & 63;
            Wt[(size_t)n*DDq + i] = f2bf(sT[d*65 + k]);
        }
    } else if (vb < 780) {
        int e = (vb - 700) * 256 + tid;
        if (e < NP * 64) {
            int k = e >> 6, d = e & 63;
            adjWb[e] = (k < Nq) ? f2bf(adjW[k*Dq + d]) : (unsigned short)0;
        }
        if (e < NP) adjBp[e] = (e < Nq) ? adjB[e] : 0.f;
    } else {
        // X [b][d][n][t] -> Xp_t bf16 [bt][64][320] and Xp_nb bf16 [n][384][64]
        // 800 blocks: (b, tile of 25), 12 n per tile, full d=64.
        unsigned short* sT = (unsigned short*)smem;   // [64][152] (144 + 8 pad)
        const int bx = vb - 780;
        const int b = bx / 25, tile = bx % 25;
        const int n0 = tile * 12;
        for (int wi = tid; wi < 64 * 36; wi += 256) {
            int jq = wi % 36, dl = wi / 36;
            float4 v = ld4(&X[(size_t)(b*64 + dl)*3600 + n0*12 + jq*4]);
            *(uint2*)&sT[dl*152 + jq*4] = make_uint2(cvtpk(v.x, v.y), cvtpk(v.z, v.w));
        }
        __syncthreads();
        // Xp_t: per (t,d) 12 contiguous n -> 3 ushort4 stores
        for (int wi = tid; wi < 12 * 64 * 3; wi += 256) {
            int cg = wi % 3, rem = wi / 3;
            int d = rem & 63, t = rem >> 6;
            ushort4 o;
            o.x = sT[d*152 + (cg*4+0)*12 + t];
            o.y = sT[d*152 + (cg*4+1)*12 + t];
            o.z = sT[d*152 + (cg*4+2)*12 + t];
            o.w = sT[d*152 + (cg*4+3)*12 + t];
            *(ushort4*)&Xp_t[((size_t)(b*Tq + t)*64 + d)*NP + n0 + cg*4] = o;
        }
        if (tile == 24) {   // zero-pad cols 300..319
            for (int wi = tid; wi < 12 * 64 * 5; wi += 256) {
                int cg = wi % 5, rem = wi / 5;
                int d = rem & 63, t = rem >> 6;
                ushort4 z; z.x = 0; z.y = 0; z.z = 0; z.w = 0;
                *(ushort4*)&Xp_t[((size_t)(b*Tq + t)*64 + d)*NP + 300 + cg*4] = z;
            }
        }
        // Xp_nb: per (nl,t) contiguous 128 B rows -> bf8 stores
        for (int wi = tid; wi < 12 * 12 * 8; wi += 256) {
            int dg = wi & 7, rem = wi >> 3;
            int t = rem % 12, nl = rem / 12;
            union { unsigned short s[8]; bf8_t v; } o;
            #pragma unroll
            for (int k = 0; k < 8; ++k) o.s[k] = sT[(dg*8+k)*152 + nl*12 + t];
            *(bf8_t*)&Xp_nb[((size_t)(n0+nl)*BTq + b*Tq + t)*64 + dg*8] = o.v;
        }
    }
}

// bf16 transpose: H_nb [n][384][64] -> H_t [bt][64][320] (cols>=300 zero)
__global__ void __launch_bounds__(256) ktr2(const unsigned short* __restrict__ Hnb,
                                            unsigned short* __restrict__ Ht) {
    __shared__ unsigned short sT[64 * 308];
    const int bt = blockIdx.x;
    const int tid = threadIdx.x;
    for (int i = tid; i < 300 * 8; i += 256) {
        int nl = i >> 3, dg = i & 7;
        bf8_t v = *(const bf8_t*)&Hnb[((size_t)nl*BTq + bt)*64 + dg*8];
        #pragma unroll
        for (int k = 0; k < 8; ++k)
            sT[(dg*8+k)*308 + nl] = (unsigned short)v[k];
    }
    __syncthreads();
    for (int wi = tid; wi < 64 * 80; wi += 256) {
        int kq = wi % 80, d = wi / 80;
        ushort4 o;
        int k = kq * 4;
        o.x = (k+0 < Nq) ? sT[d*308 + k+0] : (unsigned short)0;
        o.y = (k+1 < Nq) ? sT[d*308 + k+1] : (unsigned short)0;
        o.z = (k+2 < Nq) ? sT[d*308 + k+2] : (unsigned short)0;
        o.w = (k+3 < Nq) ? sT[d*308 + k+3] : (unsigned short)0;
        *(ushort4*)&Ht[((size_t)bt*64 + d)*NP + k] = o;
    }
}

// Fused A-recompute + aggregation (transaction-dense, R5 proven).
template<int HOP>
__global__ void __launch_bounds__(256) kfuse_t(
    const float* __restrict__ te,              // [B,N,T,D] fp32 (original input)
    unsigned short* __restrict__ teP,          // [bt][300][64] bf16 (HOP1 write / HOP2 read)
    const unsigned short* __restrict__ adjWb,  // [320][64]
    const float* __restrict__ adjBp,           // [320]
    const unsigned* __restrict__ ABt,          // tiled pairs
    const unsigned short* __restrict__ Hb_t,   // [bt][64][320]
    unsigned short* __restrict__ Hout_nb)      // [300][384][64]
{
    __shared__ unsigned short sP[80 * 72];     // 11520 B, P^T tile
    __shared__ unsigned short sT[80 * 68];     // 10880 B, te stage / out stage (aliased)
    const int bt = blockIdx.x >> 2, qi = blockIdx.x & 3;
    const int b = bt / Tq, t = bt - b * Tq;
    const int nbase = qi * 80;
    const int tid = threadIdx.x;
    const int w = tid >> 6, lane = tid & 63, quad = lane >> 4, l16 = lane & 15;
    const int dcol = w*16 + l16;
    const int nrows = (Nq - nbase < 80) ? (Nq - nbase) : 80;

    // ---- stage te (hop1, fp32->bf16) or teP (hop2) into sT, lane-contiguous
    if (HOP == 1) {
        #pragma unroll
        for (int r = 0; r < 5; ++r) {
            int row = r*16 + (tid >> 4);          // 0..79
            int col = (tid & 15) * 4;             // float idx, 16 B span per lane
            int n = nbase + row; if (n > Nq-1) n = Nq-1;
            float4 v = ld4(te + (((size_t)b*Nq + n)*Tq + t)*Dq + col);
            *(uint2*)&sT[row*68 + col] = make_uint2(cvtpk(v.x, v.y), cvtpk(v.z, v.w));
        }
    } else {
        for (int idx = tid; idx < 80*8; idx += 256) {
            int row = idx >> 3, cg = idx & 7;
            int n = nbase + row; if (n > Nq-1) n = Nq-1;
            *(bf8_t*)&sT[row*68 + cg*8] =
                *(const bf8_t*)&teP[((size_t)bt*Nq + n)*64 + cg*8];
        }
    }
    __syncthreads();
    if (HOP == 1) {
        // stream teP out of LDS (contiguous 16 B/lane)
        for (int idx = tid; idx < nrows*8; idx += 256) {
            int row = idx >> 3, cg = idx & 7;
            *(bf8_t*)&teP[((size_t)bt*Nq + nbase + row)*64 + cg*8] =
                *(const bf8_t*)&sT[row*68 + cg*8];
        }
    }
    // te fragments from LDS (B-op rows d=quad*8+j, col n=l16, per nt)
    bf8_t tb0[5], tb1[5];
    #pragma unroll
    for (int nt = 0; nt < 5; ++nt) {
        const unsigned short* tr = &sT[(nt*16 + l16)*68];
        tb0[nt] = *(const bf8_t*)(tr + quad*8);
        tb1[nt] = *(const bf8_t*)(tr + 32 + quad*8);
    }

    f4_t accO[5];
    #pragma unroll
    for (int rt = 0; rt < 5; ++rt) accO[rt] = (f4_t){0.f, 0.f, 0.f, 0.f};

    const unsigned short* hr = Hb_t + ((size_t)bt*64 + dcol)*NP;

    for (int c = 0; c < 5; ++c) {
        const int cbase = c * 64;
        const unsigned* abbase = ABt + ((((size_t)qi*5 + c)*4 + w)*5)*256 + lane*4;
        uint4 abv[5];
        #pragma unroll
        for (int nt = 0; nt < 5; ++nt) abv[nt] = *(const uint4*)(abbase + nt*256);
        const unsigned short* ar = adjWb + (cbase + w*16 + l16)*64;
        bf8_t ka0 = *(const bf8_t*)(ar + quad*8);
        bf8_t ka1 = *(const bf8_t*)(ar + 32 + quad*8);
        float4 bias4 = ld4(adjBp + cbase + w*16 + quad*4);
        bf8_t hv0 = *(const bf8_t*)(hr + cbase + quad*8);
        bf8_t hv1 = *(const bf8_t*)(hr + cbase + 32 + quad*8);

        if (c > 0) __syncthreads();   // prior consume of sP complete
        #pragma unroll
        for (int nt = 0; nt < 5; ++nt) {
            f4_t p = {0.f, 0.f, 0.f, 0.f};
            p = __builtin_amdgcn_mfma_f32_16x16x32_bf16(ka0, tb0[nt], p, 0, 0, 0);
            p = __builtin_amdgcn_mfma_f32_16x16x32_bf16(ka1, tb1[nt], p, 0, 0, 0);
            uint4 ab = abv[nt];
            float s0 = fmaxf(fmaf(__uint_as_float(ab.x << 16), __sinf(p[0] + bias4.x),
                                  __uint_as_float(ab.x & 0xFFFF0000u)), 0.f);
            float s1 = fmaxf(fmaf(__uint_as_float(ab.y << 16), __sinf(p[1] + bias4.y),
                                  __uint_as_float(ab.y & 0xFFFF0000u)), 0.f);
            float s2 = fmaxf(fmaf(__uint_as_float(ab.z << 16), __sinf(p[2] + bias4.z),
                                  __uint_as_float(ab.z & 0xFFFF0000u)), 0.f);
            float s3 = fmaxf(fmaf(__uint_as_float(ab.w << 16), __sinf(p[3] + bias4.w),
                                  __uint_as_float(ab.w & 0xFFFF0000u)), 0.f);
            *(uint2*)&sP[(nt*16 + l16)*72 + w*16 + quad*4] =
                make_uint2(cvtpk(s0, s1), cvtpk(s2, s3));
        }
        __syncthreads();
        #pragma unroll
        for (int rt = 0; rt < 5; ++rt) {
            bf8_t p0 = *(const bf8_t*)&sP[(rt*16 + l16)*72 + quad*8];
            bf8_t p1 = *(const bf8_t*)&sP[(rt*16 + l16)*72 + 32 + quad*8];
            accO[rt] = __builtin_amdgcn_mfma_f32_16x16x32_bf16(hv0, p0, accO[rt], 0, 0, 0);
            accO[rt] = __builtin_amdgcn_mfma_f32_16x16x32_bf16(hv1, p1, accO[rt], 0, 0, 0);
        }
    }
    // ---- stage output to sT (aliased), then stream out dense
    #pragma unroll
    for (int rt = 0; rt < 5; ++rt) {
        *(uint2*)&sT[(rt*16 + l16)*68 + w*16 + quad*4] =
            make_uint2(cvtpk(accO[rt][0], accO[rt][1]),
                       cvtpk(accO[rt][2], accO[rt][3]));
    }
    __syncthreads();
    for (int idx = tid; idx < nrows*8; idx += 256) {
        int row = idx >> 3, cg = idx & 7;
        *(bf8_t*)&Hout_nb[((size_t)(nbase + row)*BTq + bt)*64 + cg*8] =
            *(const bf8_t*)&sT[row*68 + cg*8];
    }
}

// Per-node matmul + gate. grid 1200 = (n, bt-quarter of 96).
__global__ void __launch_bounds__(256) kmm(
    const unsigned short* __restrict__ Hagg_nb,  // [n][384][64]
    const unsigned short* __restrict__ Xp_nb,    // [n][384][64]
    const unsigned short* __restrict__ Wt,       // [n][64][64]
    unsigned short* __restrict__ Hout_nb)        // [n][384][64]
{
    const int n = blockIdx.x >> 2, qi = blockIdx.x & 3;
    const int bt0 = qi * 96;
    const int tid = threadIdx.x;
    const int w = tid >> 6, lane = tid & 63, quad = lane >> 4, l16 = lane & 15;
    const int dcol = w*16 + l16;
    const unsigned short* wn = Wt + (size_t)n * DDq + dcol*64;
    bf8_t v0 = *(const bf8_t*)(wn + quad*8);
    bf8_t v1 = *(const bf8_t*)(wn + 32 + quad*8);
    bf8_t a0[6], a1[6];
    #pragma unroll
    for (int rt = 0; rt < 6; ++rt) {
        int r = bt0 + rt*16 + l16;
        const unsigned short* row = Hagg_nb + ((size_t)n*BTq + r)*64;
        a0[rt] = *(const bf8_t*)(row + quad*8);
        a1[rt] = *(const bf8_t*)(row + 32 + quad*8);
    }
    f4_t acc[6];
    #pragma unroll
    for (int rt = 0; rt < 6; ++rt) acc[rt] = (f4_t){0.f, 0.f, 0.f, 0.f};
    #pragma unroll
    for (int rt = 0; rt < 6; ++rt) {
        acc[rt] = __builtin_amdgcn_mfma_f32_16x16x32_bf16(v0, a0[rt], acc[rt], 0, 0, 0);
        acc[rt] = __builtin_amdgcn_mfma_f32_16x16x32_bf16(v1, a1[rt], acc[rt], 0, 0, 0);
    }
    __syncthreads();   // all reads of Hagg done before in-place overwrite
    ushort4 xp4[6];
    #pragma unroll
    for (int rt = 0; rt < 6; ++rt) {
        int r = bt0 + rt*16 + l16;
        xp4[rt] = *(const ushort4*)&Xp_nb[((size_t)n*BTq + r)*64 + w*16 + quad*4];
    }
    #pragma unroll
    for (int rt = 0; rt < 6; ++rt) {
        int r = bt0 + rt*16 + l16;
        float g0 = gatef(bf2f(xp4[rt].x) + acc[rt][0]);
        float g1 = gatef(bf2f(xp4[rt].y) + acc[rt][1]);
        float g2 = gatef(bf2f(xp4[rt].z) + acc[rt][2]);
        float g3 = gatef(bf2f(xp4[rt].w) + acc[rt][3]);
        *(uint2*)&Hout_nb[((size_t)n*BTq + r)*64 + w*16 + quad*4] =
            make_uint2(cvtpk(g0, g1), cvtpk(g2, g3));
    }
}

// GCN epilogue, transaction-dense: LDS-staged reads (1536-B chunks) and
// writes (768-B d-rows). grid 1216 = (b, n-tile 19, d-half 2).
__global__ void __launch_bounds__(256) kgcn(
    const unsigned short* __restrict__ Xp_nb, const unsigned short* __restrict__ H1_nb,
    const unsigned short* __restrict__ H2_nb, const float* __restrict__ gcnW,
    const float* __restrict__ gcnB, float* __restrict__ out)
{
    __shared__ __align__(16) char smem[16 * 816 * 2];  // 26112 B union
    unsigned short* sBuf = (unsigned short*)smem;      // [192 r][68] (r = nl*12+t)
    float* sOut = (float*)smem;                        // [32 dl][196]
    const int bid = blockIdx.x;
    const int b = bid / 38, rem2 = bid % 38;
    const int tile = rem2 >> 1, dh = rem2 & 1;
    const int n0 = tile * 16;
    const int rows = (tile == 18) ? 144 : 192;
    const int bt0 = b * Tq;
    const int tid = threadIdx.x;
    const int w = tid >> 6, lane = tid & 63, quad = lane >> 4, l16 = lane & 15;
    const int wd = w & 1, wr = w >> 1;
    const int dcol = dh*32 + wd*16 + l16;
    const float bias = gcnB[dcol];
    f4_t acc[6];
    #pragma unroll
    for (int rt = 0; rt < 6; ++rt) acc[rt] = (f4_t){0.f, 0.f, 0.f, 0.f};
    const unsigned short* bufs[3] = {Xp_nb, H1_nb, H2_nb};
    for (int c = 0; c < 3; ++c) {
        const float* gwr = gcnW + (size_t)dcol*Fq + c*Dq;
        bf8_t v0 = pack8(ld4(gwr + quad*8),      ld4(gwr + quad*8 + 4));
        bf8_t v1 = pack8(ld4(gwr + 32 + quad*8), ld4(gwr + 36 + quad*8));
        const unsigned short* buf = bufs[c];
        if (c > 0) __syncthreads();          // prior MFMA LDS reads complete
        for (int wi = tid; wi < 16*12*8; wi += 256) {
            int cg = wi & 7, rem = wi >> 3;
            int t = rem % 12, nl = rem / 12;
            int n = n0 + nl; if (n > Nq-1) n = Nq-1;
            *(bf8_t*)&sBuf[(nl*12 + t)*68 + cg*8] =
                *(const bf8_t*)&buf[((size_t)n*BTq + bt0 + t)*64 + cg*8];
        }
        __syncthreads();
        #pragma unroll
        for (int rt = 0; rt < 6; ++rt) {
            int r = (wr*6 + rt)*16 + l16;
            const unsigned short* row = &sBuf[r*68];
            bf8_t a0 = *(const bf8_t*)(row + quad*8);
            bf8_t a1 = *(const bf8_t*)(row + 32 + quad*8);
            acc[rt] = __builtin_amdgcn_mfma_f32_16x16x32_bf16(a0, v0, acc[rt], 0, 0, 0);
            acc[rt] = __builtin_amdgcn_mfma_f32_16x16x32_bf16(a1, v1, acc[rt], 0, 0, 0);
        }
    }
    __syncthreads();   // MFMA LDS reads done before alias overwrite
    const int dl = wd*16 + l16;
    #pragma unroll
    for (int rt = 0; rt < 6; ++rt) {
        int rr = (wr*6 + rt)*16;
        float4 o = make_float4(acc[rt][0] + bias, acc[rt][1] + bias,
                               acc[rt][2] + bias, acc[rt][3] + bias);
        *(float4*)&sOut[dl*196 + rr + quad*4] = o;
    }
    __syncthreads();
    float* outb = out + (size_t)(b*Dq + dh*32)*3600 + n0*12;
    const int f4max = rows >> 2;   // 48 or 36
    for (int wi = tid; wi < 32*48; wi += 256) {
        int f4i = wi % 48, dli = wi / 48;
        if (f4i < f4max)
            *(float4*)&outb[(size_t)dli*3600 + f4i*4] =
                *(const float4*)&sOut[dli*196 + f4i*4];
    }
}

extern "C" void kernel_launch(void* const* d_in, const int* in_sizes, int n_in,
                              void* d_out, int out_size, void* d_ws, size_t ws_size,
                              hipStream_t stream) {
    (void)in_sizes; (void)n_in; (void)out_size; (void)ws_size;
    const float* X    = (const float*)d_in[0];
    const float* te   = (const float*)d_in[1];
    const float* adjW = (const float*)d_in[2];
    const float* adjB = (const float*)d_in[3];
    const float* w1   = (const float*)d_in[4];
    const float* w2   = (const float*)d_in[5];
    const float* a1   = (const float*)d_in[6];
    const float* a2   = (const float*)d_in[7];
    const float* b1   = (const float*)d_in[8];
    const float* b2   = (const float*)d_in[9];
    const float* gW   = (const float*)d_in[10];
    const float* gB   = (const float*)d_in[11];
    float* out = (float*)d_out;

    char* ws = (char*)d_ws;
    unsigned*       ABt    = (unsigned*)      (ws);               //    409,600
    unsigned short* adjWb  = (unsigned short*)(ws + 409600);      //  +  40,960 =    450,560
    float*          adjBp  = (float*)         (ws + 450560);      //  +   1,280 =    451,840
    unsigned short* Wt     = (unsigned short*)(ws + 451840);      //  +2,457,600 =  2,909,440
    unsigned short* Xp_t   = (unsigned short*)(ws + 2909440);     // +15,728,640 = 18,638,080
    unsigned short* Xp_nb  = (unsigned short*)(ws + 18638080);    // +14,745,600 = 33,383,680
    unsigned short* Hagg   = (unsigned short*)(ws + 33383680);    // +14,745,600 = 48,129,280
    unsigned short* H1_nb  = (unsigned short*)(ws + 48129280);    // +14,745,600 = 62,874,880
    unsigned short* H1_t   = (unsigned short*)(ws + 62874880);    // +15,728,640 = 78,603,520
    unsigned short* teP    = (unsigned short*)(ws + 78603520);    // +14,745,600 = 93,349,120 B

    hipLaunchKernelGGL(kprep_all, dim3(1580), dim3(256), 0, stream,
                       a1, a2, b1, b2, w1, w2, adjW, adjB, X,
                       ABt, Wt, adjWb, adjBp, Xp_t, Xp_nb);
    // hop 1 (writes teP bf16 for hop 2)
    hipLaunchKernelGGL(HIP_KERNEL_NAME(kfuse_t<1>), dim3(1536), dim3(256), 0, stream,
                       te, teP, adjWb, adjBp, ABt, Xp_t, Hagg);
    hipLaunchKernelGGL(kmm,   dim3(1200), dim3(256), 0, stream, Hagg, Xp_nb, Wt, H1_nb);
    hipLaunchKernelGGL(ktr2,  dim3(384),  dim3(256), 0, stream, H1_nb, H1_t);
    // hop 2 (reads teP bf16)
    hipLaunchKernelGGL(HIP_KERNEL_NAME(kfuse_t<2>), dim3(1536), dim3(256), 0, stream,
                       te, teP, adjWb, adjBp, ABt, H1_t, Hagg);
    hipLaunchKernelGGL(kmm,   dim3(1200), dim3(256), 0, stream, Hagg, Xp_nb, Wt, Hagg); // in-place -> H2
    // gcn epilogue
    hipLaunchKernelGGL(kgcn,  dim3(1216), dim3(256), 0, stream, Xp_nb, H1_nb, Hagg, gW, gB, out);
}

// Round 8
// 279.069 us; speedup vs baseline: 1.3937x; 1.0212x over previous
//
#include <hip/hip_runtime.h>

#define Nq 300
#define Tq 12
#define Dq 64
#define Mq 16
#define BTq 384
#define DDq (Dq*Dq)      // 4096
#define Fq (Dq*3)        // 192
#define NP 320           // padded k-extent of transposed bf16 buffers

typedef short bf8_t __attribute__((ext_vector_type(8)));
typedef float f4_t  __attribute__((ext_vector_type(4)));

__device__ __forceinline__ unsigned short f2bf(float f) {
    unsigned u = __float_as_uint(f);
    u = (u + 0x7FFFu + ((u >> 16) & 1u)) >> 16;
    return (unsigned short)u;
}
__device__ __forceinline__ float bf2f(unsigned short u) {
    return __uint_as_float((unsigned)u << 16);
}
// v_cvt_pk_bf16_f32: dst[15:0]=bf16(lo), dst[31:16]=bf16(hi), RNE — identical
// bits to the f2bf bit-trick, 1 VALU instr for a pair.
__device__ __forceinline__ unsigned cvtpk(float lo, float hi) {
    unsigned r;
    asm("v_cvt_pk_bf16_f32 %0, %1, %2" : "=v"(r) : "v"(lo), "v"(hi));
    return r;
}
__device__ __forceinline__ float4 ld4(const float* p) { return *(const float4*)p; }

__device__ __forceinline__ bf8_t pack8(float4 a, float4 b) {
    union { unsigned u[4]; bf8_t v; } q;
    q.u[0] = cvtpk(a.x, a.y); q.u[1] = cvtpk(a.z, a.w);
    q.u[2] = cvtpk(b.x, b.y); q.u[3] = cvtpk(b.z, b.w);
    return q.v;
}

// sigmoid(x)*tanh(x) == u*(u-1)/(u*u+1), u=e^x (exact algebra; 1 exp not 2)
__device__ __forceinline__ float gatef(float p) {
    float pc = fminf(fmaxf(p, -30.f), 30.f);
    float u = __expf(pc);
    return u * (u - 1.f) / (u * u + 1.f);
}

// ---- Merged front-end: 1580 blocks.
__global__ void __launch_bounds__(256) kprep_all(
    const float* __restrict__ a1, const float* __restrict__ a2,
    const float* __restrict__ b1, const float* __restrict__ b2,
    const float* __restrict__ w1, const float* __restrict__ w2,
    const float* __restrict__ adjW, const float* __restrict__ adjB,
    const float* __restrict__ X,
    unsigned* __restrict__ ABt, unsigned short* __restrict__ Wt,
    unsigned short* __restrict__ adjWb, float* __restrict__ adjBp,
    unsigned short* __restrict__ Xp_t, unsigned short* __restrict__ Xp_nb)
{
    __shared__ __align__(16) char smem[64 * 308 * 2];    // 39424 B union
    const int vb = blockIdx.x;
    const int tid = threadIdx.x;

    if (vb < 400) {
        const int tile = vb;
        const int reg = tid & 3, lane = tid >> 2;
        const int nt = tile % 5;  int r1 = tile / 5;
        const int w  = r1 % 4;    int r2 = r1 / 4;
        const int c  = r2 % 5;    const int qi = r2 / 5;
        const int n = qi*80 + nt*16 + (lane & 15);
        const int k = c*64 + w*16 + (lane >> 4)*4 + reg;
        unsigned outv = 0u;
        if (n < Nq && k < Nq) {
            float sa = 0.f, sb = 0.f;
            #pragma unroll
            for (int m = 0; m < Mq; ++m) {
                sa = fmaf(a1[n*Mq+m], a2[m*Nq+k], sa);
                sb = fmaf(b1[n*Mq+m], b2[m*Nq+k], sb);
            }
            outv = cvtpk(sa, sb);   // low16 = alpha, high16 = beta
        }
        ABt[tile*256 + tid] = outv;
    } else if (vb < 700) {
        float* sT = (float*)smem;          // [64][65]
        __shared__ float sw1[Mq];
        const int n = vb - 400;
        if (tid < Mq) sw1[tid] = w1[n*Mq + tid];
        __syncthreads();
        for (int i = tid; i < DDq; i += 256) {
            int k = i >> 6, d = i & 63;
            float s = 0.f;
            #pragma unroll
            for (int m = 0; m < Mq; ++m) s = fmaf(sw1[m], w2[m*DDq + i], s);
            sT[d*65 + k] = s;
        }
        __syncthreads();
        for (int i = tid; i < DDq; i += 256) {
            int d = i >> 6, k = i & 63;
            Wt[(size_t)n*DDq + i] = f2bf(sT[d*65 + k]);
        }
    } else if (vb < 780) {
        int e = (vb - 700) * 256 + tid;
        if (e < NP * 64) {
            int k = e >> 6, d = e & 63;
            adjWb[e] = (k < Nq) ? f2bf(adjW[k*Dq + d]) : (unsigned short)0;
        }
        if (e < NP) adjBp[e] = (e < Nq) ? adjB[e] : 0.f;
    } else {
        // X [b][d][n][t] -> Xp_t bf16 [bt][64][320] and Xp_nb bf16 [n][384][64]
        unsigned short* sT = (unsigned short*)smem;   // [64][152] (144 + 8 pad)
        const int bx = vb - 780;
        const int b = bx / 25, tile = bx % 25;
        const int n0 = tile * 12;
        for (int wi = tid; wi < 64 * 36; wi += 256) {
            int jq = wi % 36, dl = wi / 36;
            float4 v = ld4(&X[(size_t)(b*64 + dl)*3600 + n0*12 + jq*4]);
            *(uint2*)&sT[dl*152 + jq*4] = make_uint2(cvtpk(v.x, v.y), cvtpk(v.z, v.w));
        }
        __syncthreads();
        for (int wi = tid; wi < 12 * 64 * 3; wi += 256) {
            int cg = wi % 3, rem = wi / 3;
            int d = rem & 63, t = rem >> 6;
            ushort4 o;
            o.x = sT[d*152 + (cg*4+0)*12 + t];
            o.y = sT[d*152 + (cg*4+1)*12 + t];
            o.z = sT[d*152 + (cg*4+2)*12 + t];
            o.w = sT[d*152 + (cg*4+3)*12 + t];
            *(ushort4*)&Xp_t[((size_t)(b*Tq + t)*64 + d)*NP + n0 + cg*4] = o;
        }
        if (tile == 24) {   // zero-pad cols 300..319
            for (int wi = tid; wi < 12 * 64 * 5; wi += 256) {
                int cg = wi % 5, rem = wi / 5;
                int d = rem & 63, t = rem >> 6;
                ushort4 z; z.x = 0; z.y = 0; z.z = 0; z.w = 0;
                *(ushort4*)&Xp_t[((size_t)(b*Tq + t)*64 + d)*NP + 300 + cg*4] = z;
            }
        }
        for (int wi = tid; wi < 12 * 12 * 8; wi += 256) {
            int dg = wi & 7, rem = wi >> 3;
            int t = rem % 12, nl = rem / 12;
            union { unsigned short s[8]; bf8_t v; } o;
            #pragma unroll
            for (int k = 0; k < 8; ++k) o.s[k] = sT[(dg*8+k)*152 + nl*12 + t];
            *(bf8_t*)&Xp_nb[((size_t)(n0+nl)*BTq + b*Tq + t)*64 + dg*8] = o.v;
        }
    }
}

// bf16 transpose: H_nb [n][384][64] -> H_t [bt][64][320] (cols>=300 zero)
__global__ void __launch_bounds__(256) ktr2(const unsigned short* __restrict__ Hnb,
                                            unsigned short* __restrict__ Ht) {
    __shared__ unsigned short sT[64 * 308];
    const int bt = blockIdx.x;
    const int tid = threadIdx.x;
    for (int i = tid; i < 300 * 8; i += 256) {
        int nl = i >> 3, dg = i & 7;
        bf8_t v = *(const bf8_t*)&Hnb[((size_t)nl*BTq + bt)*64 + dg*8];
        #pragma unroll
        for (int k = 0; k < 8; ++k)
            sT[(dg*8+k)*308 + nl] = (unsigned short)v[k];
    }
    __syncthreads();
    for (int wi = tid; wi < 64 * 80; wi += 256) {
        int kq = wi % 80, d = wi / 80;
        ushort4 o;
        int k = kq * 4;
        o.x = (k+0 < Nq) ? sT[d*308 + k+0] : (unsigned short)0;
        o.y = (k+1 < Nq) ? sT[d*308 + k+1] : (unsigned short)0;
        o.z = (k+2 < Nq) ? sT[d*308 + k+2] : (unsigned short)0;
        o.w = (k+3 < Nq) ? sT[d*308 + k+3] : (unsigned short)0;
        *(ushort4*)&Ht[((size_t)bt*64 + d)*NP + k] = o;
    }
}

// Fused A-recompute + aggregation (transaction-dense, R6 proven).
template<int HOP>
__global__ void __launch_bounds__(256) kfuse_t(
    const float* __restrict__ te,              // [B,N,T,D] fp32 (original input)
    unsigned short* __restrict__ teP,          // [bt][300][64] bf16 (HOP1 write / HOP2 read)
    const unsigned short* __restrict__ adjWb,  // [320][64]
    const float* __restrict__ adjBp,           // [320]
    const unsigned* __restrict__ ABt,          // tiled pairs
    const unsigned short* __restrict__ Hb_t,   // [bt][64][320]
    unsigned short* __restrict__ Hout_nb)      // [300][384][64]
{
    __shared__ unsigned short sP[80 * 72];     // 11520 B, P^T tile
    __shared__ unsigned short sT[80 * 68];     // 10880 B, te stage / out stage (aliased)
    const int bt = blockIdx.x >> 2, qi = blockIdx.x & 3;
    const int b = bt / Tq, t = bt - b * Tq;
    const int nbase = qi * 80;
    const int tid = threadIdx.x;
    const int w = tid >> 6, lane = tid & 63, quad = lane >> 4, l16 = lane & 15;
    const int dcol = w*16 + l16;
    const int nrows = (Nq - nbase < 80) ? (Nq - nbase) : 80;

    if (HOP == 1) {
        #pragma unroll
        for (int r = 0; r < 5; ++r) {
            int row = r*16 + (tid >> 4);          // 0..79
            int col = (tid & 15) * 4;             // float idx, 16 B span per lane
            int n = nbase + row; if (n > Nq-1) n = Nq-1;
            float4 v = ld4(te + (((size_t)b*Nq + n)*Tq + t)*Dq + col);
            *(uint2*)&sT[row*68 + col] = make_uint2(cvtpk(v.x, v.y), cvtpk(v.z, v.w));
        }
    } else {
        for (int idx = tid; idx < 80*8; idx += 256) {
            int row = idx >> 3, cg = idx & 7;
            int n = nbase + row; if (n > Nq-1) n = Nq-1;
            *(bf8_t*)&sT[row*68 + cg*8] =
                *(const bf8_t*)&teP[((size_t)bt*Nq + n)*64 + cg*8];
        }
    }
    __syncthreads();
    if (HOP == 1) {
        for (int idx = tid; idx < nrows*8; idx += 256) {
            int row = idx >> 3, cg = idx & 7;
            *(bf8_t*)&teP[((size_t)bt*Nq + nbase + row)*64 + cg*8] =
                *(const bf8_t*)&sT[row*68 + cg*8];
        }
    }
    bf8_t tb0[5], tb1[5];
    #pragma unroll
    for (int nt = 0; nt < 5; ++nt) {
        const unsigned short* tr = &sT[(nt*16 + l16)*68];
        tb0[nt] = *(const bf8_t*)(tr + quad*8);
        tb1[nt] = *(const bf8_t*)(tr + 32 + quad*8);
    }

    f4_t accO[5];
    #pragma unroll
    for (int rt = 0; rt < 5; ++rt) accO[rt] = (f4_t){0.f, 0.f, 0.f, 0.f};

    const unsigned short* hr = Hb_t + ((size_t)bt*64 + dcol)*NP;

    for (int c = 0; c < 5; ++c) {
        const int cbase = c * 64;
        const unsigned* abbase = ABt + ((((size_t)qi*5 + c)*4 + w)*5)*256 + lane*4;
        uint4 abv[5];
        #pragma unroll
        for (int nt = 0; nt < 5; ++nt) abv[nt] = *(const uint4*)(abbase + nt*256);
        const unsigned short* ar = adjWb + (cbase + w*16 + l16)*64;
        bf8_t ka0 = *(const bf8_t*)(ar + quad*8);
        bf8_t ka1 = *(const bf8_t*)(ar + 32 + quad*8);
        float4 bias4 = ld4(adjBp + cbase + w*16 + quad*4);
        bf8_t hv0 = *(const bf8_t*)(hr + cbase + quad*8);
        bf8_t hv1 = *(const bf8_t*)(hr + cbase + 32 + quad*8);

        if (c > 0) __syncthreads();   // prior consume of sP complete
        #pragma unroll
        for (int nt = 0; nt < 5; ++nt) {
            f4_t p = {0.f, 0.f, 0.f, 0.f};
            p = __builtin_amdgcn_mfma_f32_16x16x32_bf16(ka0, tb0[nt], p, 0, 0, 0);
            p = __builtin_amdgcn_mfma_f32_16x16x32_bf16(ka1, tb1[nt], p, 0, 0, 0);
            uint4 ab = abv[nt];
            float s0 = fmaxf(fmaf(__uint_as_float(ab.x << 16), __sinf(p[0] + bias4.x),
                                  __uint_as_float(ab.x & 0xFFFF0000u)), 0.f);
            float s1 = fmaxf(fmaf(__uint_as_float(ab.y << 16), __sinf(p[1] + bias4.y),
                                  __uint_as_float(ab.y & 0xFFFF0000u)), 0.f);
            float s2 = fmaxf(fmaf(__uint_as_float(ab.z << 16), __sinf(p[2] + bias4.z),
                                  __uint_as_float(ab.z & 0xFFFF0000u)), 0.f);
            float s3 = fmaxf(fmaf(__uint_as_float(ab.w << 16), __sinf(p[3] + bias4.w),
                                  __uint_as_float(ab.w & 0xFFFF0000u)), 0.f);
            *(uint2*)&sP[(nt*16 + l16)*72 + w*16 + quad*4] =
                make_uint2(cvtpk(s0, s1), cvtpk(s2, s3));
        }
        __syncthreads();
        #pragma unroll
        for (int rt = 0; rt < 5; ++rt) {
            bf8_t p0 = *(const bf8_t*)&sP[(rt*16 + l16)*72 + quad*8];
            bf8_t p1 = *(const bf8_t*)&sP[(rt*16 + l16)*72 + 32 + quad*8];
            accO[rt] = __builtin_amdgcn_mfma_f32_16x16x32_bf16(hv0, p0, accO[rt], 0, 0, 0);
            accO[rt] = __builtin_amdgcn_mfma_f32_16x16x32_bf16(hv1, p1, accO[rt], 0, 0, 0);
        }
    }
    #pragma unroll
    for (int rt = 0; rt < 5; ++rt) {
        *(uint2*)&sT[(rt*16 + l16)*68 + w*16 + quad*4] =
            make_uint2(cvtpk(accO[rt][0], accO[rt][1]),
                       cvtpk(accO[rt][2], accO[rt][3]));
    }
    __syncthreads();
    for (int idx = tid; idx < nrows*8; idx += 256) {
        int row = idx >> 3, cg = idx & 7;
        *(bf8_t*)&Hout_nb[((size_t)(nbase + row)*BTq + bt)*64 + cg*8] =
            *(const bf8_t*)&sT[row*68 + cg*8];
    }
}

// Per-node matmul + gate. grid 1800 = (n, bt-sixth of 64).
// Xp loads hoisted above MFMA chain; barrier only before in-place stores.
__global__ void __launch_bounds__(256) kmm(
    const unsigned short* __restrict__ Hagg_nb,  // [n][384][64]
    const unsigned short* __restrict__ Xp_nb,    // [n][384][64]
    const unsigned short* __restrict__ Wt,       // [n][64][64]
    unsigned short* __restrict__ Hout_nb)        // [n][384][64]
{
    const int n = blockIdx.x / 6, qi = blockIdx.x % 6;
    const int bt0 = qi * 64;
    const int tid = threadIdx.x;
    const int w = tid >> 6, lane = tid & 63, quad = lane >> 4, l16 = lane & 15;
    const unsigned short* wn = Wt + (size_t)n * DDq + (w*16 + l16)*64;
    bf8_t v0 = *(const bf8_t*)(wn + quad*8);
    bf8_t v1 = *(const bf8_t*)(wn + 32 + quad*8);
    bf8_t a0[4], a1[4];
    ushort4 xp4[4];
    #pragma unroll
    for (int rt = 0; rt < 4; ++rt) {
        int r = bt0 + rt*16 + l16;
        const unsigned short* row = Hagg_nb + ((size_t)n*BTq + r)*64;
        a0[rt] = *(const bf8_t*)(row + quad*8);
        a1[rt] = *(const bf8_t*)(row + 32 + quad*8);
        xp4[rt] = *(const ushort4*)&Xp_nb[((size_t)n*BTq + r)*64 + w*16 + quad*4];
    }
    f4_t acc[4];
    #pragma unroll
    for (int rt = 0; rt < 4; ++rt) acc[rt] = (f4_t){0.f, 0.f, 0.f, 0.f};
    #pragma unroll
    for (int rt = 0; rt < 4; ++rt) {
        acc[rt] = __builtin_amdgcn_mfma_f32_16x16x32_bf16(v0, a0[rt], acc[rt], 0, 0, 0);
        acc[rt] = __builtin_amdgcn_mfma_f32_16x16x32_bf16(v1, a1[rt], acc[rt], 0, 0, 0);
    }
    __syncthreads();   // all reads of Hagg done before in-place overwrite
    #pragma unroll
    for (int rt = 0; rt < 4; ++rt) {
        int r = bt0 + rt*16 + l16;
        float g0 = gatef(bf2f(xp4[rt].x) + acc[rt][0]);
        float g1 = gatef(bf2f(xp4[rt].y) + acc[rt][1]);
        float g2 = gatef(bf2f(xp4[rt].z) + acc[rt][2]);
        float g3 = gatef(bf2f(xp4[rt].w) + acc[rt][3]);
        *(uint2*)&Hout_nb[((size_t)n*BTq + r)*64 + w*16 + quad*4] =
            make_uint2(cvtpk(g0, g1), cvtpk(g2, g3));
    }
}

// GCN epilogue v3: row-partitioned (no read duplication) + LDS staging both ways.
// grid 1824 = (b, n-tile 19, row-group 3 of 64 r).
__global__ void __launch_bounds__(256) kgcn(
    const unsigned short* __restrict__ Xp_nb, const unsigned short* __restrict__ H1_nb,
    const unsigned short* __restrict__ H2_nb, const float* __restrict__ gcnW,
    const float* __restrict__ gcnB, float* __restrict__ out)
{
    __shared__ __align__(16) char smem[64 * 68 * 4];   // 17408 B union
    unsigned short* sBuf = (unsigned short*)smem;      // [64 r][68] bf16 (stage in)
    float* sOut = (float*)smem;                        // [64 d][68] f32 (stage out)
    const int bid = blockIdx.x;
    const int b = bid / 57, rem = bid % 57;
    const int tile = rem / 3, rg = rem % 3;
    const int n0 = tile * 16;
    const int rows = (tile == 18) ? 144 : 192;
    const int r0 = rg * 64;
    const int vrows = (rows - r0 < 64) ? (rows - r0) : 64;   // 64 or 16
    const int bt0 = b * Tq;
    const int tid = threadIdx.x;
    const int w = tid >> 6, lane = tid & 63, quad = lane >> 4, l16 = lane & 15;
    const int dcol = w*16 + l16;
    const float bias = gcnB[dcol];
    f4_t acc[4];
    #pragma unroll
    for (int rt = 0; rt < 4; ++rt) acc[rt] = (f4_t){0.f, 0.f, 0.f, 0.f};
    const unsigned short* bufs[3] = {Xp_nb, H1_nb, H2_nb};
    for (int c = 0; c < 3; ++c) {
        const float* gwr = gcnW + (size_t)dcol*Fq + c*Dq;
        bf8_t v0 = pack8(ld4(gwr + quad*8),      ld4(gwr + quad*8 + 4));
        bf8_t v1 = pack8(ld4(gwr + 32 + quad*8), ld4(gwr + 36 + quad*8));
        const unsigned short* buf = bufs[c];
        if (c > 0) __syncthreads();          // prior MFMA LDS reads complete
        // stage this block's OWN 64 rows only (reads partitioned across rg)
        for (int wi = tid; wi < 64*8; wi += 256) {
            int cg = wi & 7, rl = wi >> 3;
            int rgl = r0 + rl;
            int n = n0 + rgl / 12, t = rgl % 12;
            if (n > Nq-1) n = Nq-1;
            *(bf8_t*)&sBuf[rl*68 + cg*8] =
                *(const bf8_t*)&buf[((size_t)n*BTq + bt0 + t)*64 + cg*8];
        }
        __syncthreads();
        #pragma unroll
        for (int rt = 0; rt < 4; ++rt) {
            const unsigned short* row = &sBuf[(rt*16 + l16)*68];
            bf8_t a0 = *(const bf8_t*)(row + quad*8);
            bf8_t a1 = *(const bf8_t*)(row + 32 + quad*8);
            acc[rt] = __builtin_amdgcn_mfma_f32_16x16x32_bf16(a0, v0, acc[rt], 0, 0, 0);
            acc[rt] = __builtin_amdgcn_mfma_f32_16x16x32_bf16(a1, v1, acc[rt], 0, 0, 0);
        }
    }
    __syncthreads();   // MFMA LDS reads done before alias overwrite
    #pragma unroll
    for (int rt = 0; rt < 4; ++rt) {
        float4 o = make_float4(acc[rt][0] + bias, acc[rt][1] + bias,
                               acc[rt][2] + bias, acc[rt][3] + bias);
        *(float4*)&sOut[dcol*68 + rt*16 + quad*4] = o;
    }
    __syncthreads();
    float* outb = out + (size_t)b*Dq*3600 + n0*12 + r0;
    const int f4max = vrows >> 2;   // 16 or 4
    for (int wi = tid; wi < 64*16; wi += 256) {
        int f4i = wi & 15, dli = wi >> 4;
        if (f4i < f4max)
            *(float4*)&outb[(size_t)dli*3600 + f4i*4] =
                *(const float4*)&sOut[dli*68 + f4i*4];
    }
}

extern "C" void kernel_launch(void* const* d_in, const int* in_sizes, int n_in,
                              void* d_out, int out_size, void* d_ws, size_t ws_size,
                              hipStream_t stream) {
    (void)in_sizes; (void)n_in; (void)out_size; (void)ws_size;
    const float* X    = (const float*)d_in[0];
    const float* te   = (const float*)d_in[1];
    const float* adjW = (const float*)d_in[2];
    const float* adjB = (const float*)d_in[3];
    const float* w1   = (const float*)d_in[4];
    const float* w2   = (const float*)d_in[5];
    const float* a1   = (const float*)d_in[6];
    const float* a2   = (const float*)d_in[7];
    const float* b1   = (const float*)d_in[8];
    const float* b2   = (const float*)d_in[9];
    const float* gW   = (const float*)d_in[10];
    const float* gB   = (const float*)d_in[11];
    float* out = (float*)d_out;

    char* ws = (char*)d_ws;
    unsigned*       ABt    = (unsigned*)      (ws);               //    409,600
    unsigned short* adjWb  = (unsigned short*)(ws + 409600);      //  +  40,960 =    450,560
    float*          adjBp  = (float*)         (ws + 450560);      //  +   1,280 =    451,840
    unsigned short* Wt     = (unsigned short*)(ws + 451840);      //  +2,457,600 =  2,909,440
    unsigned short* Xp_t   = (unsigned short*)(ws + 2909440);     // +15,728,640 = 18,638,080
    unsigned short* Xp_nb  = (unsigned short*)(ws + 18638080);    // +14,745,600 = 33,383,680
    unsigned short* Hagg   = (unsigned short*)(ws + 33383680);    // +14,745,600 = 48,129,280
    unsigned short* H1_nb  = (unsigned short*)(ws + 48129280);    // +14,745,600 = 62,874,880
    unsigned short* H1_t   = (unsigned short*)(ws + 62874880);    // +15,728,640 = 78,603,520
    unsigned short* teP    = (unsigned short*)(ws + 78603520);    // +14,745,600 = 93,349,120 B

    hipLaunchKernelGGL(kprep_all, dim3(1580), dim3(256), 0, stream,
                       a1, a2, b1, b2, w1, w2, adjW, adjB, X,
                       ABt, Wt, adjWb, adjBp, Xp_t, Xp_nb);
    // hop 1 (writes teP bf16 for hop 2)
    hipLaunchKernelGGL(HIP_KERNEL_NAME(kfuse_t<1>), dim3(1536), dim3(256), 0, stream,
                       te, teP, adjWb, adjBp, ABt, Xp_t, Hagg);
    hipLaunchKernelGGL(kmm,   dim3(1800), dim3(256), 0, stream, Hagg, Xp_nb, Wt, H1_nb);
    hipLaunchKernelGGL(ktr2,  dim3(384),  dim3(256), 0, stream, H1_nb, H1_t);
    // hop 2 (reads teP bf16)
    hipLaunchKernelGGL(HIP_KERNEL_NAME(kfuse_t<2>), dim3(1536), dim3(256), 0, stream,
                       te, teP, adjWb, adjBp, ABt, H1_t, Hagg);
    hipLaunchKernelGGL(kmm,   dim3(1800), dim3(256), 0, stream, Hagg, Xp_nb, Wt, Hagg); // in-place -> H2
    // gcn epilogue
    hipLaunchKernelGGL(kgcn,  dim3(1824), dim3(256), 0, stream, Xp_nb, H1_nb, Hagg, gW, gB, out);
}